// Round 2
// baseline (8312.331 us; speedup 1.0000x reference)
//
#include <hip/hip_runtime.h>
#include <hip/hip_bf16.h>

#define N_NODES 3072
#define S_SINK  256
#define DIN     64
#define DM      256
#define NHEAD   8
#define DHEAD   32
#define NLAYER  3
#define DFF_    1024

static __device__ __forceinline__ float gelu_exact(float v) {
    return 0.5f * v * (1.0f + erff(v * 0.70710678118654752f));
}

// ---------------- node encode: h = x@Wp.T + b + pe ----------------
__global__ __launch_bounds__(256) void node_encode_kernel(
    const float* __restrict__ x, const float* __restrict__ C,
    const unsigned char* __restrict__ mask,
    const float* __restrict__ Wp, const float* __restrict__ bp,
    const float* __restrict__ peW, const float* __restrict__ peb,
    const float* __restrict__ peg, const float* __restrict__ pebt,
    const float* __restrict__ gate,
    float* __restrict__ h)
{
    int i = blockIdx.x, t = threadIdx.x;
    __shared__ float xs[DIN];
    __shared__ float r1[256], r2[256];
    __shared__ float zs[20];
    if (t < DIN) xs[t] = x[i * DIN + t];
    float c  = C[i * 256 + t];
    float cc = fminf(fmaxf(c, 0.0f), 1.0f);
    r1[t] = cc; r2[t] = cc * cc;
    __syncthreads();
    for (int s = 128; s > 0; s >>= 1) { if (t < s) { r1[t] += r1[t + s]; r2[t] += r2[t + s]; } __syncthreads(); }
    float cm  = r1[0] * (1.0f / 256.0f);
    float cms = r2[0] * (1.0f / 256.0f);
    __syncthreads();
    r1[t] = cc; r2[t] = cc;
    __syncthreads();
    for (int s = 128; s > 0; s >>= 1) { if (t < s) { r1[t] = fmaxf(r1[t], r1[t + s]); r2[t] = fminf(r2[t], r2[t + s]); } __syncthreads(); }
    float cmax = r1[0], cmin = r2[0];
    __syncthreads();
    if (t == 0) {
        float var  = fmaxf(cms - cm * cm, 0.0f);
        float cstd = sqrtf(var);
        zs[0] = cm; zs[1] = cmax; zs[2] = cmin; zs[3] = cstd;
        float w = 0.15f + 1e-6f;
        for (int k = 0; k < 8; ++k) {
            float ck = (float)k / 7.0f;
            float d1 = (cm   - ck) / w;
            float d2 = (cmax - ck) / w;
            zs[4 + k]  = expf(-0.5f * d1 * d1);
            zs[12 + k] = expf(-0.5f * d2 * d2);
        }
    }
    __syncthreads();
    float pl = peb[t];
    #pragma unroll
    for (int f = 0; f < 20; ++f) pl += zs[f] * peW[t * 20 + f];
    r1[t] = pl; r2[t] = pl * pl;
    __syncthreads();
    for (int s = 128; s > 0; s >>= 1) { if (t < s) { r1[t] += r1[t + s]; r2[t] += r2[t + s]; } __syncthreads(); }
    float m  = r1[0] * (1.0f / 256.0f);
    float vv = fmaxf(r2[0] * (1.0f / 256.0f) - m * m, 0.0f);
    float pe = (pl - m) * rsqrtf(vv + 1e-5f) * peg[t] + pebt[t];
    pe *= gate[0];
    if (mask[i] != 0) pe = 0.0f;
    float hv = bp[t];
    #pragma unroll
    for (int k = 0; k < DIN; ++k) hv += xs[k] * Wp[t * DIN + k];
    h[(size_t)i * 256 + t] = hv + pe;
}

// ---------------- Cn = C / (||C||+1e-6) ----------------
__global__ __launch_bounds__(256) void cn_kernel(const float* __restrict__ C, float* __restrict__ Cn) {
    int i = blockIdx.x, t = threadIdx.x;
    __shared__ float r1[256];
    float v = C[(size_t)i * 256 + t];
    r1[t] = v * v;
    __syncthreads();
    for (int s = 128; s > 0; s >>= 1) { if (t < s) r1[t] += r1[t + s]; __syncthreads(); }
    float nrm = sqrtf(r1[0]) + 1e-6f;
    Cn[(size_t)i * 256 + t] = v / nrm;
}

// ---------------- CT[s][j] = C[j][s] ----------------
__global__ __launch_bounds__(256) void transpose_kernel(const float* __restrict__ C, float* __restrict__ CT) {
    __shared__ float tile[32][33];
    int bx = blockIdx.x * 32;              // node dim
    int by = blockIdx.y * 32;              // sink dim
    int tx = threadIdx.x & 31, ty = threadIdx.x >> 5;
    #pragma unroll
    for (int r = 0; r < 4; ++r) {
        int row = bx + ty + r * 8;
        tile[ty + r * 8][tx] = C[(size_t)row * 256 + by + tx];
    }
    __syncthreads();
    #pragma unroll
    for (int r = 0; r < 4; ++r) {
        int srow = by + ty + r * 8;
        CT[(size_t)srow * 3072 + bx + tx] = tile[tx][ty + r * 8];
    }
}

// ---------------- gather rows ----------------
__global__ __launch_bounds__(256) void gather_kernel(const float* __restrict__ h, const int* __restrict__ idx,
                                                     float* __restrict__ sg) {
    int s = blockIdx.x, t = threadIdx.x;
    sg[(size_t)s * 256 + t] = h[(size_t)idx[s] * 256 + t];
}

// ---------------- LayerNorm over 256 channels ----------------
__global__ __launch_bounds__(256) void ln_kernel(const float* __restrict__ in, const float* __restrict__ g,
                                                 const float* __restrict__ b, float* __restrict__ out) {
    int i = blockIdx.x, t = threadIdx.x;
    __shared__ float r1[256], r2[256];
    float v = in[(size_t)i * 256 + t];
    r1[t] = v; r2[t] = v * v;
    __syncthreads();
    for (int s = 128; s > 0; s >>= 1) { if (t < s) { r1[t] += r1[t + s]; r2[t] += r2[t + s]; } __syncthreads(); }
    float m  = r1[0] * (1.0f / 256.0f);
    float vv = fmaxf(r2[0] * (1.0f / 256.0f) - m * m, 0.0f);
    out[(size_t)i * 256 + t] = (v - m) * rsqrtf(vv + 1e-5f) * g[t] + b[t];
}

// final LN -> d_out as FLOAT32 (reference output dtype is float32)
__global__ __launch_bounds__(256) void ln_out_kernel(const float* __restrict__ in, const float* __restrict__ g,
                                                     const float* __restrict__ b, float* __restrict__ out) {
    int i = blockIdx.x, t = threadIdx.x;
    __shared__ float r1[256], r2[256];
    float v = in[(size_t)i * 256 + t];
    r1[t] = v; r2[t] = v * v;
    __syncthreads();
    for (int s = 128; s > 0; s >>= 1) { if (t < s) { r1[t] += r1[t + s]; r2[t] += r2[t + s]; } __syncthreads(); }
    float m  = r1[0] * (1.0f / 256.0f);
    float vv = fmaxf(r2[0] * (1.0f / 256.0f) - m * m, 0.0f);
    out[(size_t)i * 256 + t] = (v - m) * rsqrtf(vv + 1e-5f) * g[t] + b[t];
}

// ---------------- generic fp32 GEMM: out = epi(scale*(A @ W^T) + bias) + res ----------------
// A [M,K] lda; W [N,K] row-major; out [M,N] ldo. M,N multiples of 64; K multiple of 16.
__global__ __launch_bounds__(256) void gemm_kernel(
    const float* __restrict__ A, int lda,
    const float* __restrict__ W,
    const float* __restrict__ bias,
    const float* __restrict__ res,
    const float* __restrict__ scale,
    float* __restrict__ out, int ldo,
    int K, int act)
{
    __shared__ float As[64][17];
    __shared__ float Ws[64][17];
    int tid = threadIdx.x;
    int tx = tid & 15, ty = tid >> 4;
    int row0 = blockIdx.y * 64, col0 = blockIdx.x * 64;
    int lr = tid >> 2, lc = (tid & 3) << 2;
    const float* Ap = A + (size_t)(row0 + lr) * lda + lc;
    const float* Wp = W + (size_t)(col0 + lr) * K + lc;
    float acc[4][4] = {};
    for (int k0 = 0; k0 < K; k0 += 16) {
        float4 av = *reinterpret_cast<const float4*>(Ap + k0);
        float4 wv = *reinterpret_cast<const float4*>(Wp + k0);
        As[lr][lc + 0] = av.x; As[lr][lc + 1] = av.y; As[lr][lc + 2] = av.z; As[lr][lc + 3] = av.w;
        Ws[lr][lc + 0] = wv.x; Ws[lr][lc + 1] = wv.y; Ws[lr][lc + 2] = wv.z; Ws[lr][lc + 3] = wv.w;
        __syncthreads();
        #pragma unroll
        for (int kk = 0; kk < 16; ++kk) {
            float a[4], b[4];
            #pragma unroll
            for (int u = 0; u < 4; ++u) a[u] = As[ty * 4 + u][kk];
            #pragma unroll
            for (int u = 0; u < 4; ++u) b[u] = Ws[tx * 4 + u][kk];
            #pragma unroll
            for (int ii = 0; ii < 4; ++ii)
                #pragma unroll
                for (int jj = 0; jj < 4; ++jj)
                    acc[ii][jj] += a[ii] * b[jj];
        }
        __syncthreads();
    }
    float sc = scale ? *scale : 1.0f;
    #pragma unroll
    for (int ii = 0; ii < 4; ++ii) {
        int r = row0 + ty * 4 + ii;
        #pragma unroll
        for (int jj = 0; jj < 4; ++jj) {
            int cidx = col0 + tx * 4 + jj;
            float v = acc[ii][jj] * sc;
            if (bias) v += bias[cidx];
            if (act)  v = gelu_exact(v);
            if (res)  v += res[(size_t)r * ldo + cidx];
            out[(size_t)r * ldo + cidx] = v;
        }
    }
}

// ---------------- fused biased MHA row kernel: one wave per (head, query row) ----------------
// Lk hardcoded 3072. scores = qk/sqrt(32) + bmat[i*ldb+j]*(*bscale) - 10000*mask[j]
// exact reference softmax: exp(max(s - rowmax, -20)) / sum
__global__ __launch_bounds__(64) void attn_kernel(
    const float* __restrict__ Q, int ldq,
    const float* __restrict__ Km, int ldk,
    const float* __restrict__ Vm, int ldv,
    const float* __restrict__ bmat, int ldb,
    const float* __restrict__ bscale,
    const unsigned char* __restrict__ mask,
    float* __restrict__ out, int ldo)
{
    __shared__ float smem[3072];
    __shared__ float qs[32];
    int head = blockIdx.x, i = blockIdx.y, lane = threadIdx.x;
    if (lane < 32) qs[lane] = Q[(size_t)i * ldq + head * 32 + lane];
    __syncthreads();
    float q[32];
    #pragma unroll
    for (int c = 0; c < 32; ++c) q[c] = qs[c];
    float bsc = bscale ? *bscale : 1.0f;
    const float rs = 0.17677669529663687f; // 1/sqrt(32)

    float mmax = -1e30f;
    for (int j = lane; j < 3072; j += 64) {
        const float4* kp = reinterpret_cast<const float4*>(Km + (size_t)j * ldk + head * 32);
        float d0 = 0, d1 = 0, d2 = 0, d3 = 0;
        #pragma unroll
        for (int u = 0; u < 8; ++u) {
            float4 kv = kp[u];
            d0 += q[4 * u + 0] * kv.x; d1 += q[4 * u + 1] * kv.y;
            d2 += q[4 * u + 2] * kv.z; d3 += q[4 * u + 3] * kv.w;
        }
        float sv = (d0 + d1 + d2 + d3) * rs + bmat[(size_t)i * ldb + j] * bsc;
        sv -= 10000.0f * (float)mask[j];
        smem[j] = sv;
        mmax = fmaxf(mmax, sv);
    }
    #pragma unroll
    for (int o = 32; o > 0; o >>= 1) mmax = fmaxf(mmax, __shfl_xor(mmax, o));
    __syncthreads();
    float lsum = 0.0f;
    for (int j = lane; j < 3072; j += 64) {
        float pv = expf(fmaxf(smem[j] - mmax, -20.0f));  // == reference clip(-20,20) semantics
        smem[j] = pv;
        lsum += pv;
    }
    #pragma unroll
    for (int o = 32; o > 0; o >>= 1) lsum += __shfl_xor(lsum, o);
    float den = lsum;
    float acc[32];
    #pragma unroll
    for (int c = 0; c < 32; ++c) acc[c] = 0.0f;
    __syncthreads();
    for (int j = lane; j < 3072; j += 64) {
        float pv = smem[j];
        const float4* vp = reinterpret_cast<const float4*>(Vm + (size_t)j * ldv + head * 32);
        #pragma unroll
        for (int u = 0; u < 8; ++u) {
            float4 vv = vp[u];
            acc[4 * u + 0] += pv * vv.x; acc[4 * u + 1] += pv * vv.y;
            acc[4 * u + 2] += pv * vv.z; acc[4 * u + 3] += pv * vv.w;
        }
    }
    __syncthreads();
    // stage [64][33] into smem and tree-reduce across lanes
    #pragma unroll
    for (int c = 0; c < 32; ++c) smem[lane * 33 + c] = acc[c];
    __syncthreads();
    int c = lane & 31, half = lane >> 5;
    float tsum = 0.0f;
    #pragma unroll
    for (int jj = 0; jj < 32; ++jj) tsum += smem[(half * 32 + jj) * 33 + c];
    tsum += __shfl_xor(tsum, 32);
    if (lane < 32) out[(size_t)i * ldo + head * 32 + c] = tsum / den;
}

extern "C" void kernel_launch(void* const* d_in, const int* in_sizes, int n_in,
                              void* d_out, int out_size, void* d_ws, size_t ws_size,
                              hipStream_t stream)
{
    const float* x        = (const float*)d_in[0];
    const float* C        = (const float*)d_in[1];
    const int*   sidx     = (const int*)d_in[2];
    const unsigned char* mask = (const unsigned char*)d_in[3];
    const float* proj_W   = (const float*)d_in[4];
    const float* proj_b   = (const float*)d_in[5];
    const float* peW      = (const float*)d_in[6];
    const float* peb      = (const float*)d_in[7];
    const float* peg      = (const float*)d_in[8];
    const float* pebt     = (const float*)d_in[9];
    const float* pe_gate  = (const float*)d_in[10];
    const float* alpha_nn = (const float*)d_in[11];
    const float* beta_sn  = (const float*)d_in[12];
    const float* sqW      = (const float*)d_in[13];
    const float* sqb      = (const float*)d_in[14];
    const float* sn_Win   = (const float*)d_in[15];
    const float* sn_bin   = (const float*)d_in[16];
    const float* sn_Wout  = (const float*)d_in[17];
    const float* sn_bout  = (const float*)d_in[18];
    const float* nn_Win   = (const float*)d_in[19];
    const float* nn_bin   = (const float*)d_in[20];
    const float* nn_Wout  = (const float*)d_in[21];
    const float* nn_bout  = (const float*)d_in[22];
    const float* ln_s_g   = (const float*)d_in[23];
    const float* ln_s_b   = (const float*)d_in[24];
    const float* ln_n1_g  = (const float*)d_in[25];
    const float* ln_n1_b  = (const float*)d_in[26];
    const float* ln_n2_g  = (const float*)d_in[27];
    const float* ln_n2_b  = (const float*)d_in[28];
    const float* ffn_W1   = (const float*)d_in[29];
    const float* ffn_b1   = (const float*)d_in[30];
    const float* ffn_W2   = (const float*)d_in[31];
    const float* ffn_b2   = (const float*)d_in[32];
    const float* ffs_W1   = (const float*)d_in[33];
    const float* ffs_b1   = (const float*)d_in[34];
    const float* ffs_W2   = (const float*)d_in[35];
    const float* ffs_b2   = (const float*)d_in[36];
    const float* ln_og    = (const float*)d_in[37];
    const float* ln_ob    = (const float*)d_in[38];

    float* ws    = (float*)d_ws;
    float* h     = ws;                 // 786432
    float* hn    = ws + 786432;        // 786432
    float* big   = ws + 1572864;       // 3145728 (union)
    float* attno = ws + 4718592;       // 786432
    float* biasnn= ws + 5505024;       // 9437184
    float* Cn    = ws + 14942208;      // 786432
    float* CT    = ws + 15728640;      // 786432
    float* sinkq = ws + 16515072;      // 65536
    float* sqn   = ws + 16580608;      // 65536
    float* sg    = ws + 16646144;      // 65536
    // big union: sink phase {q_s, kv_s, mid_s}; node phase {qkv}; ffn phase {mid_n}
    float* q_s   = big;
    float* kv_s  = big + 65536;        // 3072 x 512
    float* mid_s = big + 1638400;      // 256 x 1024
    float* qkv   = big;                // 3072 x 768
    float* mid_n = big;                // 3072 x 1024

    dim3 b256(256), b64(64);

    node_encode_kernel<<<N_NODES, b256, 0, stream>>>(x, C, mask, proj_W, proj_b, peW, peb, peg, pebt, pe_gate, h);
    gather_kernel<<<S_SINK, b256, 0, stream>>>(h, sidx, sg);
    gemm_kernel<<<dim3(4, 4), b256, 0, stream>>>(sg, 256, sqW, sqb, nullptr, nullptr, sinkq, 256, 256, 0);
    cn_kernel<<<N_NODES, b256, 0, stream>>>(C, Cn);
    transpose_kernel<<<dim3(96, 8), b256, 0, stream>>>(C, CT);
    gemm_kernel<<<dim3(48, 48), b256, 0, stream>>>(Cn, 256, Cn, nullptr, nullptr, alpha_nn, biasnn, 3072, 256, 0);

    for (int l = 0; l < NLAYER; ++l) {
        const float* Win_s  = sn_Win  + (size_t)l * 768 * 256;
        const float* bin_s  = sn_bin  + l * 768;
        const float* Wout_s = sn_Wout + (size_t)l * 256 * 256;
        const float* bout_s = sn_bout + l * 256;
        const float* Win_n  = nn_Win  + (size_t)l * 768 * 256;
        const float* bin_n  = nn_bin  + l * 768;
        const float* Wout_n = nn_Wout + (size_t)l * 256 * 256;
        const float* bout_n = nn_bout + l * 256;

        // ---- sink branch ----
        ln_kernel<<<S_SINK, b256, 0, stream>>>(sinkq, ln_s_g + l * 256, ln_s_b + l * 256, sqn);
        gemm_kernel<<<dim3(4, 4), b256, 0, stream>>>(sqn, 256, Win_s, bin_s, nullptr, nullptr, q_s, 256, 256, 0);
        gemm_kernel<<<dim3(8, 48), b256, 0, stream>>>(h, 256, Win_s + 256 * 256, bin_s + 256, nullptr, nullptr, kv_s, 512, 256, 0);
        attn_kernel<<<dim3(NHEAD, S_SINK), b64, 0, stream>>>(q_s, 256, kv_s, 512, kv_s + 256, 512, CT, 3072, beta_sn, mask, attno, 256);
        gemm_kernel<<<dim3(4, 4), b256, 0, stream>>>(attno, 256, Wout_s, bout_s, sinkq, nullptr, sinkq, 256, 256, 0);
        gemm_kernel<<<dim3(16, 4), b256, 0, stream>>>(sinkq, 256, ffs_W1 + (size_t)l * 262144, ffs_b1 + l * 1024, nullptr, nullptr, mid_s, 1024, 256, 1);
        gemm_kernel<<<dim3(4, 4), b256, 0, stream>>>(mid_s, 1024, ffs_W2 + (size_t)l * 262144, ffs_b2 + l * 256, sinkq, nullptr, sinkq, 256, 1024, 0);

        // ---- node branch ----
        ln_kernel<<<N_NODES, b256, 0, stream>>>(h, ln_n1_g + l * 256, ln_n1_b + l * 256, hn);
        gemm_kernel<<<dim3(12, 48), b256, 0, stream>>>(hn, 256, Win_n, bin_n, nullptr, nullptr, qkv, 768, 256, 0);
        attn_kernel<<<dim3(NHEAD, N_NODES), b64, 0, stream>>>(qkv, 768, qkv + 256, 768, qkv + 512, 768, biasnn, 3072, nullptr, mask, attno, 256);
        gemm_kernel<<<dim3(4, 48), b256, 0, stream>>>(attno, 256, Wout_n, bout_n, h, nullptr, h, 256, 256, 0);
        ln_kernel<<<N_NODES, b256, 0, stream>>>(h, ln_n2_g + l * 256, ln_n2_b + l * 256, hn);
        gemm_kernel<<<dim3(16, 48), b256, 0, stream>>>(hn, 256, ffn_W1 + (size_t)l * 262144, ffn_b1 + l * 1024, nullptr, nullptr, mid_n, 1024, 256, 1);
        gemm_kernel<<<dim3(4, 48), b256, 0, stream>>>(mid_n, 1024, ffn_W2 + (size_t)l * 262144, ffn_b2 + l * 256, h, nullptr, h, 256, 1024, 0);
    }

    ln_out_kernel<<<S_SINK, b256, 0, stream>>>(sinkq, ln_og, ln_ob, (float*)d_out);
}

// Round 3
// 2003.384 us; speedup vs baseline: 4.1491x; 4.1491x over previous
//
#include <hip/hip_runtime.h>
#include <hip/hip_bf16.h>

#define N_NODES 3072
#define S_SINK  256
#define DIN     64
#define DM      256
#define NHEAD   8
#define DHEAD   32
#define NLAYER  3
#define DFF_    1024

typedef __attribute__((ext_vector_type(8))) short short8v;
typedef __attribute__((ext_vector_type(4))) float f32x4;

static __device__ __forceinline__ float gelu_exact(float v) {
    return 0.5f * v * (1.0f + erff(v * 0.70710678118654752f));
}
static __device__ __forceinline__ unsigned short f2b_rne(float f) {
    unsigned int b = __float_as_uint(f);
    b += 0x7fffu + ((b >> 16) & 1u);
    return (unsigned short)(b >> 16);
}

// ---------------- node encode: h = x@Wp.T + b + pe ----------------
__global__ __launch_bounds__(256) void node_encode_kernel(
    const float* __restrict__ x, const float* __restrict__ C,
    const unsigned char* __restrict__ mask,
    const float* __restrict__ Wp, const float* __restrict__ bp,
    const float* __restrict__ peW, const float* __restrict__ peb,
    const float* __restrict__ peg, const float* __restrict__ pebt,
    const float* __restrict__ gate,
    float* __restrict__ h)
{
    int i = blockIdx.x, t = threadIdx.x;
    __shared__ float xs[DIN];
    __shared__ float r1[256], r2[256];
    __shared__ float zs[20];
    if (t < DIN) xs[t] = x[i * DIN + t];
    float c  = C[i * 256 + t];
    float cc = fminf(fmaxf(c, 0.0f), 1.0f);
    r1[t] = cc; r2[t] = cc * cc;
    __syncthreads();
    for (int s = 128; s > 0; s >>= 1) { if (t < s) { r1[t] += r1[t + s]; r2[t] += r2[t + s]; } __syncthreads(); }
    float cm  = r1[0] * (1.0f / 256.0f);
    float cms = r2[0] * (1.0f / 256.0f);
    __syncthreads();
    r1[t] = cc; r2[t] = cc;
    __syncthreads();
    for (int s = 128; s > 0; s >>= 1) { if (t < s) { r1[t] = fmaxf(r1[t], r1[t + s]); r2[t] = fminf(r2[t], r2[t + s]); } __syncthreads(); }
    float cmax = r1[0], cmin = r2[0];
    __syncthreads();
    if (t == 0) {
        float var  = fmaxf(cms - cm * cm, 0.0f);
        float cstd = sqrtf(var);
        zs[0] = cm; zs[1] = cmax; zs[2] = cmin; zs[3] = cstd;
        float w = 0.15f + 1e-6f;
        for (int k = 0; k < 8; ++k) {
            float ck = (float)k / 7.0f;
            float d1 = (cm   - ck) / w;
            float d2 = (cmax - ck) / w;
            zs[4 + k]  = expf(-0.5f * d1 * d1);
            zs[12 + k] = expf(-0.5f * d2 * d2);
        }
    }
    __syncthreads();
    float pl = peb[t];
    #pragma unroll
    for (int f = 0; f < 20; ++f) pl += zs[f] * peW[t * 20 + f];
    r1[t] = pl; r2[t] = pl * pl;
    __syncthreads();
    for (int s = 128; s > 0; s >>= 1) { if (t < s) { r1[t] += r1[t + s]; r2[t] += r2[t + s]; } __syncthreads(); }
    float m  = r1[0] * (1.0f / 256.0f);
    float vv = fmaxf(r2[0] * (1.0f / 256.0f) - m * m, 0.0f);
    float pe = (pl - m) * rsqrtf(vv + 1e-5f) * peg[t] + pebt[t];
    pe *= gate[0];
    if (mask[i] != 0) pe = 0.0f;
    float hv = bp[t];
    #pragma unroll
    for (int k = 0; k < DIN; ++k) hv += xs[k] * Wp[t * DIN + k];
    h[(size_t)i * 256 + t] = hv + pe;
}

// ---------------- Cn = C / (||C||+1e-6) ----------------
__global__ __launch_bounds__(256) void cn_kernel(const float* __restrict__ C, float* __restrict__ Cn) {
    int i = blockIdx.x, t = threadIdx.x;
    __shared__ float r1[256];
    float v = C[(size_t)i * 256 + t];
    r1[t] = v * v;
    __syncthreads();
    for (int s = 128; s > 0; s >>= 1) { if (t < s) r1[t] += r1[t + s]; __syncthreads(); }
    float nrm = sqrtf(r1[0]) + 1e-6f;
    Cn[(size_t)i * 256 + t] = v / nrm;
}

// ---------------- maskadd[j] = -10000 * mask[j] ----------------
__global__ __launch_bounds__(256) void maskadd_kernel(const unsigned char* __restrict__ mask, float* __restrict__ ma) {
    int j = blockIdx.x * 256 + threadIdx.x;
    if (j < N_NODES) ma[j] = -10000.0f * (float)mask[j];
}

// ---------------- CTb[s][j] = bf16(beta*C[j][s] + maskadd[j]) ----------------
__global__ __launch_bounds__(256) void transpose_b16_kernel(const float* __restrict__ C, const float* __restrict__ beta,
                                                            const float* __restrict__ maskadd, unsigned short* __restrict__ CTb) {
    __shared__ float tile[32][33];
    int bx = blockIdx.x * 32;              // node dim
    int by = blockIdx.y * 32;              // sink dim
    int tx = threadIdx.x & 31, ty = threadIdx.x >> 5;
    float bt = beta[0];
    #pragma unroll
    for (int r = 0; r < 4; ++r) {
        int row = bx + ty + r * 8;
        tile[ty + r * 8][tx] = C[(size_t)row * 256 + by + tx];
    }
    __syncthreads();
    #pragma unroll
    for (int r = 0; r < 4; ++r) {
        int srow = by + ty + r * 8;
        CTb[(size_t)srow * 3072 + bx + tx] = f2b_rne(bt * tile[tx][ty + r * 8] + maskadd[bx + tx]);
    }
}

// ---------------- gather rows ----------------
__global__ __launch_bounds__(256) void gather_kernel(const float* __restrict__ h, const int* __restrict__ idx,
                                                     float* __restrict__ sg) {
    int s = blockIdx.x, t = threadIdx.x;
    sg[(size_t)s * 256 + t] = h[(size_t)idx[s] * 256 + t];
}

// ---------------- LayerNorm over 256 channels ----------------
__global__ __launch_bounds__(256) void ln_kernel(const float* __restrict__ in, const float* __restrict__ g,
                                                 const float* __restrict__ b, float* __restrict__ out) {
    int i = blockIdx.x, t = threadIdx.x;
    __shared__ float r1[256], r2[256];
    float v = in[(size_t)i * 256 + t];
    r1[t] = v; r2[t] = v * v;
    __syncthreads();
    for (int s = 128; s > 0; s >>= 1) { if (t < s) { r1[t] += r1[t + s]; r2[t] += r2[t + s]; } __syncthreads(); }
    float m  = r1[0] * (1.0f / 256.0f);
    float vv = fmaxf(r2[0] * (1.0f / 256.0f) - m * m, 0.0f);
    out[(size_t)i * 256 + t] = (v - m) * rsqrtf(vv + 1e-5f) * g[t] + b[t];
}

// ---------------- generic fp32 GEMM: out = epi(scale*(A @ W^T) + bias) + res ----------------
__global__ __launch_bounds__(256) void gemm_kernel(
    const float* __restrict__ A, int lda,
    const float* __restrict__ W,
    const float* __restrict__ bias,
    const float* __restrict__ res,
    const float* __restrict__ scale,
    float* __restrict__ out, int ldo,
    int K, int act)
{
    __shared__ float As[64][17];
    __shared__ float Ws[64][17];
    int tid = threadIdx.x;
    int tx = tid & 15, ty = tid >> 4;
    int row0 = blockIdx.y * 64, col0 = blockIdx.x * 64;
    int lr = tid >> 2, lc = (tid & 3) << 2;
    const float* Ap = A + (size_t)(row0 + lr) * lda + lc;
    const float* Wp = W + (size_t)(col0 + lr) * K + lc;
    float acc[4][4] = {};
    for (int k0 = 0; k0 < K; k0 += 16) {
        float4 av = *reinterpret_cast<const float4*>(Ap + k0);
        float4 wv = *reinterpret_cast<const float4*>(Wp + k0);
        As[lr][lc + 0] = av.x; As[lr][lc + 1] = av.y; As[lr][lc + 2] = av.z; As[lr][lc + 3] = av.w;
        Ws[lr][lc + 0] = wv.x; Ws[lr][lc + 1] = wv.y; Ws[lr][lc + 2] = wv.z; Ws[lr][lc + 3] = wv.w;
        __syncthreads();
        #pragma unroll
        for (int kk = 0; kk < 16; ++kk) {
            float a[4], b[4];
            #pragma unroll
            for (int u = 0; u < 4; ++u) a[u] = As[ty * 4 + u][kk];
            #pragma unroll
            for (int u = 0; u < 4; ++u) b[u] = Ws[tx * 4 + u][kk];
            #pragma unroll
            for (int ii = 0; ii < 4; ++ii)
                #pragma unroll
                for (int jj = 0; jj < 4; ++jj)
                    acc[ii][jj] += a[ii] * b[jj];
        }
        __syncthreads();
    }
    float sc = scale ? *scale : 1.0f;
    #pragma unroll
    for (int ii = 0; ii < 4; ++ii) {
        int r = row0 + ty * 4 + ii;
        #pragma unroll
        for (int jj = 0; jj < 4; ++jj) {
            int cidx = col0 + tx * 4 + jj;
            float v = acc[ii][jj] * sc;
            if (bias) v += bias[cidx];
            if (act)  v = gelu_exact(v);
            if (res)  v += res[(size_t)r * ldo + cidx];
            out[(size_t)r * ldo + cidx] = v;
        }
    }
}

// ---------------- fp32 GEMM with bf16 output + per-col fp32 bias (for biasnn) ----------------
__global__ __launch_bounds__(256) void gemm_b16_kernel(
    const float* __restrict__ A, int lda,
    const float* __restrict__ W,
    const float* __restrict__ colbias,
    const float* __restrict__ scale,
    unsigned short* __restrict__ out, int ldo,
    int K)
{
    __shared__ float As[64][17];
    __shared__ float Ws[64][17];
    int tid = threadIdx.x;
    int tx = tid & 15, ty = tid >> 4;
    int row0 = blockIdx.y * 64, col0 = blockIdx.x * 64;
    int lr = tid >> 2, lc = (tid & 3) << 2;
    const float* Ap = A + (size_t)(row0 + lr) * lda + lc;
    const float* Wp = W + (size_t)(col0 + lr) * K + lc;
    float acc[4][4] = {};
    for (int k0 = 0; k0 < K; k0 += 16) {
        float4 av = *reinterpret_cast<const float4*>(Ap + k0);
        float4 wv = *reinterpret_cast<const float4*>(Wp + k0);
        As[lr][lc + 0] = av.x; As[lr][lc + 1] = av.y; As[lr][lc + 2] = av.z; As[lr][lc + 3] = av.w;
        Ws[lr][lc + 0] = wv.x; Ws[lr][lc + 1] = wv.y; Ws[lr][lc + 2] = wv.z; Ws[lr][lc + 3] = wv.w;
        __syncthreads();
        #pragma unroll
        for (int kk = 0; kk < 16; ++kk) {
            float a[4], b[4];
            #pragma unroll
            for (int u = 0; u < 4; ++u) a[u] = As[ty * 4 + u][kk];
            #pragma unroll
            for (int u = 0; u < 4; ++u) b[u] = Ws[tx * 4 + u][kk];
            #pragma unroll
            for (int ii = 0; ii < 4; ++ii)
                #pragma unroll
                for (int jj = 0; jj < 4; ++jj)
                    acc[ii][jj] += a[ii] * b[jj];
        }
        __syncthreads();
    }
    float sc = scale ? *scale : 1.0f;
    #pragma unroll
    for (int ii = 0; ii < 4; ++ii) {
        int r = row0 + ty * 4 + ii;
        #pragma unroll
        for (int jj = 0; jj < 4; ++jj) {
            int cidx = col0 + tx * 4 + jj;
            float v = acc[ii][jj] * sc;
            if (colbias) v += colbias[cidx];
            out[(size_t)r * ldo + cidx] = f2b_rne(v);
        }
    }
}

// ---------------- prep: K/V slices of src -> K_bf16[h][key][32], VT_bf16[h][32][3072] ----------------
__global__ __launch_bounds__(256) void prep_kv_kernel(const float* __restrict__ src, int ld, int koff, int voff,
                                                      unsigned short* __restrict__ Kb, unsigned short* __restrict__ VTb)
{
    int h = blockIdx.y, k0 = blockIdx.x * 64, t = threadIdx.x;
    __shared__ float tl[64][33];
    #pragma unroll
    for (int it = 0; it < 8; ++it) {
        int idx = t + 256 * it;
        int j = idx >> 5, d = idx & 31;
        Kb[((size_t)h * 3072 + k0 + j) * 32 + d] = f2b_rne(src[(size_t)(k0 + j) * ld + koff + h * 32 + d]);
        tl[j][d] = src[(size_t)(k0 + j) * ld + voff + h * 32 + d];
    }
    __syncthreads();
    #pragma unroll
    for (int it = 0; it < 8; ++it) {
        int idx = t + 256 * it;
        int d = idx >> 6, j = idx & 63;
        VTb[((size_t)h * 32 + d) * 3072 + k0 + j] = f2b_rne(tl[j][d]);
    }
}

// ---------------- MFMA flash attention (swapped operands), 1 wave per (32 q, head) ----------------
// S^T = K.Qt via mfma(Kfrag, Qfrag); online softmax lane-local per q; O^T = Vt.Pt.
__global__ __launch_bounds__(64) void attn_mfma_kernel(
    const float* __restrict__ Q, int ldq,
    const unsigned short* __restrict__ Kb,
    const unsigned short* __restrict__ VTb,
    const unsigned short* __restrict__ biasb,
    float* __restrict__ out)
{
    __shared__ unsigned short P_lds[32 * 72];
    const int head = blockIdx.y;
    const int i0 = blockIdx.x * 32;
    const int lane = threadIdx.x;
    const int c15 = lane & 15, g = lane >> 4;
    const unsigned short* Kh  = Kb  + (size_t)head * 3072 * 32;
    const unsigned short* VTh = VTb + (size_t)head * 32 * 3072;
    const f32x4 zf = {0.f, 0.f, 0.f, 0.f};
    const float rs = 0.17677669529663687f;

    // Q fragments (B operand of S^T): lane holds q=nf*16+c15, d = g*8..g*8+7
    short8v qf[2];
    #pragma unroll
    for (int nf = 0; nf < 2; ++nf) {
        const float* qp = Q + (size_t)(i0 + nf * 16 + c15) * ldq + head * 32 + g * 8;
        short8v v;
        #pragma unroll
        for (int j = 0; j < 8; ++j) v[j] = (short)f2b_rne(qp[j]);
        qf[nf] = v;
    }

    float m_[2] = {-1e30f, -1e30f};
    float l_[2] = {0.f, 0.f};
    f32x4 acc[2][2];
    #pragma unroll
    for (int a = 0; a < 2; ++a)
        #pragma unroll
        for (int b = 0; b < 2; ++b) acc[a][b] = zf;

    for (int kt = 0; kt < 48; ++kt) {
        const int k0 = kt * 64;
        // K A-fragments: lane holds key=k0+mf*16+c15, d = g*8..
        short8v kf[4];
        #pragma unroll
        for (int mf = 0; mf < 4; ++mf)
            kf[mf] = *(const short8v*)(Kh + (size_t)(k0 + mf * 16 + c15) * 32 + g * 8);
        // S^T tiles
        f32x4 s[4][2];
        #pragma unroll
        for (int mf = 0; mf < 4; ++mf)
            #pragma unroll
            for (int nf = 0; nf < 2; ++nf)
                s[mf][nf] = __builtin_amdgcn_mfma_f32_16x16x32_bf16(kf[mf], qf[nf], zf, 0, 0, 0);
        // scale + bias (bias[q][key] bf16, has beta/alpha & mask folded in)
        #pragma unroll
        for (int nf = 0; nf < 2; ++nf) {
            const unsigned short* bp = biasb + (size_t)(i0 + nf * 16 + c15) * 3072 + k0;
            #pragma unroll
            for (int mf = 0; mf < 4; ++mf) {
                uint2 bv = *(const uint2*)(bp + mf * 16 + g * 4);
                float b0 = __uint_as_float(bv.x << 16);
                float b1 = __uint_as_float(bv.x & 0xffff0000u);
                float b2 = __uint_as_float(bv.y << 16);
                float b3 = __uint_as_float(bv.y & 0xffff0000u);
                s[mf][nf][0] = s[mf][nf][0] * rs + b0;
                s[mf][nf][1] = s[mf][nf][1] * rs + b1;
                s[mf][nf][2] = s[mf][nf][2] * rs + b2;
                s[mf][nf][3] = s[mf][nf][3] * rs + b3;
            }
        }
        // online softmax; P -> LDS bf16
        #pragma unroll
        for (int nf = 0; nf < 2; ++nf) {
            float tmax = -1e30f;
            #pragma unroll
            for (int mf = 0; mf < 4; ++mf)
                #pragma unroll
                for (int r = 0; r < 4; ++r) tmax = fmaxf(tmax, s[mf][nf][r]);
            tmax = fmaxf(tmax, __shfl_xor(tmax, 16));
            tmax = fmaxf(tmax, __shfl_xor(tmax, 32));
            float mn = fmaxf(m_[nf], tmax);
            float sc = __expf(m_[nf] - mn);
            m_[nf] = mn;
            float ts = 0.f;
            #pragma unroll
            for (int mf = 0; mf < 4; ++mf)
                #pragma unroll
                for (int r = 0; r < 4; ++r) {
                    float p = __expf(s[mf][nf][r] - mn);
                    s[mf][nf][r] = p;
                    ts += p;
                }
            ts += __shfl_xor(ts, 16);
            ts += __shfl_xor(ts, 32);
            l_[nf] = l_[nf] * sc + ts;
            #pragma unroll
            for (int mf = 0; mf < 2; ++mf) {
                acc[mf][nf][0] *= sc; acc[mf][nf][1] *= sc;
                acc[mf][nf][2] *= sc; acc[mf][nf][3] *= sc;
            }
            const int q = nf * 16 + c15;
            #pragma unroll
            for (int mf = 0; mf < 4; ++mf) {
                uint2 pv;
                pv.x = (unsigned)f2b_rne(s[mf][nf][0]) | ((unsigned)f2b_rne(s[mf][nf][1]) << 16);
                pv.y = (unsigned)f2b_rne(s[mf][nf][2]) | ((unsigned)f2b_rne(s[mf][nf][3]) << 16);
                *(uint2*)(P_lds + q * 72 + mf * 16 + g * 4) = pv;
            }
        }
        // O^T += V^T . P^T
        #pragma unroll
        for (int ks = 0; ks < 2; ++ks) {
            short8v pB[2], vA[2];
            #pragma unroll
            for (int nf = 0; nf < 2; ++nf)
                pB[nf] = *(const short8v*)(P_lds + (nf * 16 + c15) * 72 + ks * 32 + g * 8);
            #pragma unroll
            for (int mf = 0; mf < 2; ++mf)
                vA[mf] = *(const short8v*)(VTh + (size_t)(mf * 16 + c15) * 3072 + k0 + ks * 32 + g * 8);
            #pragma unroll
            for (int mf = 0; mf < 2; ++mf)
                #pragma unroll
                for (int nf = 0; nf < 2; ++nf)
                    acc[mf][nf] = __builtin_amdgcn_mfma_f32_16x16x32_bf16(vA[mf], pB[nf], acc[mf][nf], 0, 0, 0);
        }
    }
    // epilogue: normalize, transpose O^T -> [q][d] via LDS, coalesced store
    float* O_lds = (float*)P_lds;   // [32][36]
    #pragma unroll
    for (int nf = 0; nf < 2; ++nf) {
        float inv = 1.0f / l_[nf];
        int q = nf * 16 + c15;
        #pragma unroll
        for (int mf = 0; mf < 2; ++mf) {
            f32x4 v = acc[mf][nf];
            v[0] *= inv; v[1] *= inv; v[2] *= inv; v[3] *= inv;
            *(f32x4*)(O_lds + q * 36 + mf * 16 + g * 4) = v;
        }
    }
    int q = lane >> 1, half = lane & 1;
    const float* orow = O_lds + q * 36 + half * 16;
    float* op = out + (size_t)(i0 + q) * 256 + head * 32 + half * 16;
    #pragma unroll
    for (int u = 0; u < 4; ++u)
        *(float4*)(op + u * 4) = *(const float4*)(orow + u * 4);
}

// final LN -> d_out as float32
__global__ __launch_bounds__(256) void ln_out_kernel(const float* __restrict__ in, const float* __restrict__ g,
                                                     const float* __restrict__ b, float* __restrict__ out) {
    int i = blockIdx.x, t = threadIdx.x;
    __shared__ float r1[256], r2[256];
    float v = in[(size_t)i * 256 + t];
    r1[t] = v; r2[t] = v * v;
    __syncthreads();
    for (int s = 128; s > 0; s >>= 1) { if (t < s) { r1[t] += r1[t + s]; r2[t] += r2[t + s]; } __syncthreads(); }
    float m  = r1[0] * (1.0f / 256.0f);
    float vv = fmaxf(r2[0] * (1.0f / 256.0f) - m * m, 0.0f);
    out[(size_t)i * 256 + t] = (v - m) * rsqrtf(vv + 1e-5f) * g[t] + b[t];
}

extern "C" void kernel_launch(void* const* d_in, const int* in_sizes, int n_in,
                              void* d_out, int out_size, void* d_ws, size_t ws_size,
                              hipStream_t stream)
{
    const float* x        = (const float*)d_in[0];
    const float* C        = (const float*)d_in[1];
    const int*   sidx     = (const int*)d_in[2];
    const unsigned char* mask = (const unsigned char*)d_in[3];
    const float* proj_W   = (const float*)d_in[4];
    const float* proj_b   = (const float*)d_in[5];
    const float* peW      = (const float*)d_in[6];
    const float* peb      = (const float*)d_in[7];
    const float* peg      = (const float*)d_in[8];
    const float* pebt     = (const float*)d_in[9];
    const float* pe_gate  = (const float*)d_in[10];
    const float* alpha_nn = (const float*)d_in[11];
    const float* beta_sn  = (const float*)d_in[12];
    const float* sqW      = (const float*)d_in[13];
    const float* sqb      = (const float*)d_in[14];
    const float* sn_Win   = (const float*)d_in[15];
    const float* sn_bin   = (const float*)d_in[16];
    const float* sn_Wout  = (const float*)d_in[17];
    const float* sn_bout  = (const float*)d_in[18];
    const float* nn_Win   = (const float*)d_in[19];
    const float* nn_bin   = (const float*)d_in[20];
    const float* nn_Wout  = (const float*)d_in[21];
    const float* nn_bout  = (const float*)d_in[22];
    const float* ln_s_g   = (const float*)d_in[23];
    const float* ln_s_b   = (const float*)d_in[24];
    const float* ln_n1_g  = (const float*)d_in[25];
    const float* ln_n1_b  = (const float*)d_in[26];
    const float* ln_n2_g  = (const float*)d_in[27];
    const float* ln_n2_b  = (const float*)d_in[28];
    const float* ffn_W1   = (const float*)d_in[29];
    const float* ffn_b1   = (const float*)d_in[30];
    const float* ffn_W2   = (const float*)d_in[31];
    const float* ffn_b2   = (const float*)d_in[32];
    const float* ffs_W1   = (const float*)d_in[33];
    const float* ffs_b1   = (const float*)d_in[34];
    const float* ffs_W2   = (const float*)d_in[35];
    const float* ffs_b2   = (const float*)d_in[36];
    const float* ln_og    = (const float*)d_in[37];
    const float* ln_ob    = (const float*)d_in[38];

    float* ws = (float*)d_ws;
    float* h      = ws;                     // 786432
    float* hn     = ws +   786432;          // 786432
    float* big    = ws +  1572864;          // 3145728 (union)
    float* attno  = ws +  4718592;          // 786432
    unsigned short* biasb = (unsigned short*)(ws + 5505024);   // 3072x3072 bf16 (4718592 floats)
    float* Cn     = ws + 10223616;          // 786432
    unsigned short* CTb = (unsigned short*)(ws + 11010048);    // 256x3072 bf16 (393216 floats)
    unsigned short* Kb  = (unsigned short*)(ws + 11403264);    // 8x3072x32 bf16 (393216 floats)
    unsigned short* VTb = (unsigned short*)(ws + 11796480);    // 8x32x3072 bf16 (393216 floats)
    float* maskadd= ws + 12189696;          // 4096
    float* sinkq  = ws + 12193792;          // 65536
    float* sqn    = ws + 12259328;          // 65536
    float* sg     = ws + 12324864;          // 65536
    // big union:
    float* q_s   = big;                     // 256x256
    float* kv_s  = big + 65536;             // 3072x512
    float* mid_s = big + 1638400;           // 256x1024
    float* qkv   = big;                     // 3072x768
    float* mid_n = big;                     // 3072x1024

    dim3 b256(256), b64(64);

    maskadd_kernel<<<12, b256, 0, stream>>>(mask, maskadd);
    node_encode_kernel<<<N_NODES, b256, 0, stream>>>(x, C, mask, proj_W, proj_b, peW, peb, peg, pebt, pe_gate, h);
    gather_kernel<<<S_SINK, b256, 0, stream>>>(h, sidx, sg);
    gemm_kernel<<<dim3(4, 4), b256, 0, stream>>>(sg, 256, sqW, sqb, nullptr, nullptr, sinkq, 256, 256, 0);
    cn_kernel<<<N_NODES, b256, 0, stream>>>(C, Cn);
    transpose_b16_kernel<<<dim3(96, 8), b256, 0, stream>>>(C, beta_sn, maskadd, CTb);
    gemm_b16_kernel<<<dim3(48, 48), b256, 0, stream>>>(Cn, 256, Cn, maskadd, alpha_nn, biasb, 3072, 256);

    for (int l = 0; l < NLAYER; ++l) {
        const float* Win_s  = sn_Win  + (size_t)l * 768 * 256;
        const float* bin_s  = sn_bin  + l * 768;
        const float* Wout_s = sn_Wout + (size_t)l * 256 * 256;
        const float* bout_s = sn_bout + l * 256;
        const float* Win_n  = nn_Win  + (size_t)l * 768 * 256;
        const float* bin_n  = nn_bin  + l * 768;
        const float* Wout_n = nn_Wout + (size_t)l * 256 * 256;
        const float* bout_n = nn_bout + l * 256;

        // ---- sink branch ----
        ln_kernel<<<S_SINK, b256, 0, stream>>>(sinkq, ln_s_g + l * 256, ln_s_b + l * 256, sqn);
        gemm_kernel<<<dim3(4, 4), b256, 0, stream>>>(sqn, 256, Win_s, bin_s, nullptr, nullptr, q_s, 256, 256, 0);
        gemm_kernel<<<dim3(8, 48), b256, 0, stream>>>(h, 256, Win_s + 256 * 256, bin_s + 256, nullptr, nullptr, kv_s, 512, 256, 0);
        prep_kv_kernel<<<dim3(48, 8), b256, 0, stream>>>(kv_s, 512, 0, 256, Kb, VTb);
        attn_mfma_kernel<<<dim3(8, 8), b64, 0, stream>>>(q_s, 256, Kb, VTb, CTb, attno);
        gemm_kernel<<<dim3(4, 4), b256, 0, stream>>>(attno, 256, Wout_s, bout_s, sinkq, nullptr, sinkq, 256, 256, 0);
        gemm_kernel<<<dim3(16, 4), b256, 0, stream>>>(sinkq, 256, ffs_W1 + (size_t)l * 262144, ffs_b1 + l * 1024, nullptr, nullptr, mid_s, 1024, 256, 1);
        gemm_kernel<<<dim3(4, 4), b256, 0, stream>>>(mid_s, 1024, ffs_W2 + (size_t)l * 262144, ffs_b2 + l * 256, sinkq, nullptr, sinkq, 256, 1024, 0);

        // ---- node branch ----
        ln_kernel<<<N_NODES, b256, 0, stream>>>(h, ln_n1_g + l * 256, ln_n1_b + l * 256, hn);
        gemm_kernel<<<dim3(12, 48), b256, 0, stream>>>(hn, 256, Win_n, bin_n, nullptr, nullptr, qkv, 768, 256, 0);
        prep_kv_kernel<<<dim3(48, 8), b256, 0, stream>>>(qkv, 768, 256, 512, Kb, VTb);
        attn_mfma_kernel<<<dim3(96, 8), b64, 0, stream>>>(qkv, 768, Kb, VTb, biasb, attno);
        gemm_kernel<<<dim3(4, 48), b256, 0, stream>>>(attno, 256, Wout_n, bout_n, h, nullptr, h, 256, 256, 0);
        ln_kernel<<<N_NODES, b256, 0, stream>>>(h, ln_n2_g + l * 256, ln_n2_b + l * 256, hn);
        gemm_kernel<<<dim3(16, 48), b256, 0, stream>>>(hn, 256, ffn_W1 + (size_t)l * 262144, ffn_b1 + l * 1024, nullptr, nullptr, mid_n, 1024, 256, 1);
        gemm_kernel<<<dim3(4, 48), b256, 0, stream>>>(mid_n, 1024, ffn_W2 + (size_t)l * 262144, ffn_b2 + l * 256, h, nullptr, h, 256, 1024, 0);
    }

    ln_out_kernel<<<S_SINK, b256, 0, stream>>>(sinkq, ln_og, ln_ob, (float*)d_out);
}

// Round 4
// 769.046 us; speedup vs baseline: 10.8086x; 2.6050x over previous
//
#include <hip/hip_runtime.h>
#include <hip/hip_bf16.h>

#define N_NODES 3072
#define S_SINK  256
#define DIN     64

typedef __attribute__((ext_vector_type(8))) short short8v;
typedef __attribute__((ext_vector_type(4))) float f32x4;

static __device__ __forceinline__ float gelu_exact(float v) {
    return 0.5f * v * (1.0f + erff(v * 0.70710678118654752f));
}
static __device__ __forceinline__ unsigned short f2b_rne(float f) {
    unsigned int b = __float_as_uint(f);
    b += 0x7fffu + ((b >> 16) & 1u);
    return (unsigned short)(b >> 16);
}

// ---------------- node encode: h = x@Wp.T + b + pe ----------------
__global__ __launch_bounds__(256) void node_encode_kernel(
    const float* __restrict__ x, const float* __restrict__ C,
    const unsigned char* __restrict__ mask,
    const float* __restrict__ Wp, const float* __restrict__ bp,
    const float* __restrict__ peW, const float* __restrict__ peb,
    const float* __restrict__ peg, const float* __restrict__ pebt,
    const float* __restrict__ gate,
    float* __restrict__ h)
{
    int i = blockIdx.x, t = threadIdx.x;
    __shared__ float xs[DIN];
    __shared__ float r1[256], r2[256];
    __shared__ float zs[20];
    if (t < DIN) xs[t] = x[i * DIN + t];
    float c  = C[i * 256 + t];
    float cc = fminf(fmaxf(c, 0.0f), 1.0f);
    r1[t] = cc; r2[t] = cc * cc;
    __syncthreads();
    for (int s = 128; s > 0; s >>= 1) { if (t < s) { r1[t] += r1[t + s]; r2[t] += r2[t + s]; } __syncthreads(); }
    float cm  = r1[0] * (1.0f / 256.0f);
    float cms = r2[0] * (1.0f / 256.0f);
    __syncthreads();
    r1[t] = cc; r2[t] = cc;
    __syncthreads();
    for (int s = 128; s > 0; s >>= 1) { if (t < s) { r1[t] = fmaxf(r1[t], r1[t + s]); r2[t] = fminf(r2[t], r2[t + s]); } __syncthreads(); }
    float cmax = r1[0], cmin = r2[0];
    __syncthreads();
    if (t == 0) {
        float var  = fmaxf(cms - cm * cm, 0.0f);
        float cstd = sqrtf(var);
        zs[0] = cm; zs[1] = cmax; zs[2] = cmin; zs[3] = cstd;
        float w = 0.15f + 1e-6f;
        for (int k = 0; k < 8; ++k) {
            float ck = (float)k / 7.0f;
            float d1 = (cm   - ck) / w;
            float d2 = (cmax - ck) / w;
            zs[4 + k]  = expf(-0.5f * d1 * d1);
            zs[12 + k] = expf(-0.5f * d2 * d2);
        }
    }
    __syncthreads();
    float pl = peb[t];
    #pragma unroll
    for (int f = 0; f < 20; ++f) pl += zs[f] * peW[t * 20 + f];
    r1[t] = pl; r2[t] = pl * pl;
    __syncthreads();
    for (int s = 128; s > 0; s >>= 1) { if (t < s) { r1[t] += r1[t + s]; r2[t] += r2[t + s]; } __syncthreads(); }
    float m  = r1[0] * (1.0f / 256.0f);
    float vv = fmaxf(r2[0] * (1.0f / 256.0f) - m * m, 0.0f);
    float pe = (pl - m) * rsqrtf(vv + 1e-5f) * peg[t] + pebt[t];
    pe *= gate[0];
    if (mask[i] != 0) pe = 0.0f;
    float hv = bp[t];
    #pragma unroll
    for (int k = 0; k < DIN; ++k) hv += xs[k] * Wp[t * DIN + k];
    h[(size_t)i * 256 + t] = hv + pe;
}

// ---------------- Cn = C / (||C||+1e-6) ----------------
__global__ __launch_bounds__(256) void cn_kernel(const float* __restrict__ C, float* __restrict__ Cn) {
    int i = blockIdx.x, t = threadIdx.x;
    __shared__ float r1[256];
    float v = C[(size_t)i * 256 + t];
    r1[t] = v * v;
    __syncthreads();
    for (int s = 128; s > 0; s >>= 1) { if (t < s) r1[t] += r1[t + s]; __syncthreads(); }
    float nrm = sqrtf(r1[0]) + 1e-6f;
    Cn[(size_t)i * 256 + t] = v / nrm;
}

// ---------------- maskadd[j] = -10000 * mask[j] ----------------
__global__ __launch_bounds__(256) void maskadd_kernel(const unsigned char* __restrict__ mask, float* __restrict__ ma) {
    int j = blockIdx.x * 256 + threadIdx.x;
    if (j < N_NODES) ma[j] = -10000.0f * (float)mask[j];
}

// ---------------- CTb[s][j] = bf16(beta*C[j][s] + maskadd[j]) ----------------
__global__ __launch_bounds__(256) void transpose_b16_kernel(const float* __restrict__ C, const float* __restrict__ beta,
                                                            const float* __restrict__ maskadd, unsigned short* __restrict__ CTb) {
    __shared__ float tile[32][33];
    int bx = blockIdx.x * 32;              // node dim
    int by = blockIdx.y * 32;              // sink dim
    int tx = threadIdx.x & 31, ty = threadIdx.x >> 5;
    float bt = beta[0];
    #pragma unroll
    for (int r = 0; r < 4; ++r) {
        int row = bx + ty + r * 8;
        tile[ty + r * 8][tx] = C[(size_t)row * 256 + by + tx];
    }
    __syncthreads();
    #pragma unroll
    for (int r = 0; r < 4; ++r) {
        int srow = by + ty + r * 8;
        CTb[(size_t)srow * 3072 + bx + tx] = f2b_rne(bt * tile[tx][ty + r * 8] + maskadd[bx + tx]);
    }
}

// ---------------- gather rows -> bf16 ----------------
__global__ __launch_bounds__(256) void gather_b16_kernel(const float* __restrict__ h, const int* __restrict__ idx,
                                                         unsigned short* __restrict__ sg) {
    int s = blockIdx.x, t = threadIdx.x;
    sg[(size_t)s * 256 + t] = f2b_rne(h[(size_t)idx[s] * 256 + t]);
}

// ---------------- LayerNorm over 256 channels -> bf16 ----------------
__global__ __launch_bounds__(256) void ln_b16_kernel(const float* __restrict__ in, const float* __restrict__ g,
                                                     const float* __restrict__ b, unsigned short* __restrict__ out) {
    int i = blockIdx.x, t = threadIdx.x;
    __shared__ float r1[256], r2[256];
    float v = in[(size_t)i * 256 + t];
    r1[t] = v; r2[t] = v * v;
    __syncthreads();
    for (int s = 128; s > 0; s >>= 1) { if (t < s) { r1[t] += r1[t + s]; r2[t] += r2[t + s]; } __syncthreads(); }
    float m  = r1[0] * (1.0f / 256.0f);
    float vv = fmaxf(r2[0] * (1.0f / 256.0f) - m * m, 0.0f);
    out[(size_t)i * 256 + t] = f2b_rne((v - m) * rsqrtf(vv + 1e-5f) * g[t] + b[t]);
}

// final LN -> d_out as float32
__global__ __launch_bounds__(256) void ln_out_kernel(const float* __restrict__ in, const float* __restrict__ g,
                                                     const float* __restrict__ b, float* __restrict__ out) {
    int i = blockIdx.x, t = threadIdx.x;
    __shared__ float r1[256], r2[256];
    float v = in[(size_t)i * 256 + t];
    r1[t] = v; r2[t] = v * v;
    __syncthreads();
    for (int s = 128; s > 0; s >>= 1) { if (t < s) { r1[t] += r1[t + s]; r2[t] += r2[t + s]; } __syncthreads(); }
    float m  = r1[0] * (1.0f / 256.0f);
    float vv = fmaxf(r2[0] * (1.0f / 256.0f) - m * m, 0.0f);
    out[(size_t)i * 256 + t] = (v - m) * rsqrtf(vv + 1e-5f) * g[t] + b[t];
}

// ---------------- staging load helper: 8 elems -> bf16x8 ----------------
static __device__ __forceinline__ short8v ld8_cvt(const void* base, size_t off, int isf32) {
    if (isf32) {
        const float* p = (const float*)base + off;
        float4 a = *(const float4*)p;
        float4 b = *(const float4*)(p + 4);
        short8v v;
        v[0] = (short)f2b_rne(a.x); v[1] = (short)f2b_rne(a.y);
        v[2] = (short)f2b_rne(a.z); v[3] = (short)f2b_rne(a.w);
        v[4] = (short)f2b_rne(b.x); v[5] = (short)f2b_rne(b.y);
        v[6] = (short)f2b_rne(b.z); v[7] = (short)f2b_rne(b.w);
        return v;
    }
    return *(const short8v*)((const unsigned short*)base + off);
}

// ---------------- MFMA GEMM: out = epi(scale*(A@W^T) + bias) [+res] ----------------
// A [M,lda] f32 or bf16; W [N,ldw] f32 or bf16 row-major. 64x64 tile, 4 waves, BK=64.
// out f32 or bf16 (out_b16). M,N mult of 64, K mult of 64.
__global__ __launch_bounds__(256) void gemm_mfma_kernel(
    const void* __restrict__ A_, int lda, int af32,
    const void* __restrict__ W_, int ldw, int wf32,
    const float* __restrict__ bias,
    const float* __restrict__ res,
    const float* __restrict__ scale,
    void* __restrict__ out_, int ldo, int out_b16,
    int K, int act)
{
    __shared__ unsigned short As[64][72];
    __shared__ unsigned short Ws[64][72];
    int tid = threadIdx.x;
    int lane = tid & 63, wid = tid >> 6;
    int c15 = lane & 15, g = lane >> 4;
    int wm = wid & 1, wn = wid >> 1;
    int row0 = blockIdx.y * 64, col0 = blockIdx.x * 64;
    f32x4 acc[2][2];
    const f32x4 zf = {0.f, 0.f, 0.f, 0.f};
    acc[0][0] = zf; acc[0][1] = zf; acc[1][0] = zf; acc[1][1] = zf;

    for (int k0 = 0; k0 < K; k0 += 64) {
        #pragma unroll
        for (int hh = 0; hh < 2; ++hh) {
            int cid = tid + hh * 256;
            int rr = cid >> 3, cc = (cid & 7) * 8;
            short8v va = ld8_cvt(A_, (size_t)(row0 + rr) * lda + k0 + cc, af32);
            short8v vw = ld8_cvt(W_, (size_t)(col0 + rr) * ldw + k0 + cc, wf32);
            *(short8v*)(&As[rr][cc]) = va;
            *(short8v*)(&Ws[rr][cc]) = vw;
        }
        __syncthreads();
        #pragma unroll
        for (int ks = 0; ks < 2; ++ks) {
            short8v a0 = *(const short8v*)(&As[wm * 32 + c15][ks * 32 + g * 8]);
            short8v a1 = *(const short8v*)(&As[wm * 32 + 16 + c15][ks * 32 + g * 8]);
            short8v w0 = *(const short8v*)(&Ws[wn * 32 + c15][ks * 32 + g * 8]);
            short8v w1 = *(const short8v*)(&Ws[wn * 32 + 16 + c15][ks * 32 + g * 8]);
            acc[0][0] = __builtin_amdgcn_mfma_f32_16x16x32_bf16(a0, w0, acc[0][0], 0, 0, 0);
            acc[0][1] = __builtin_amdgcn_mfma_f32_16x16x32_bf16(a0, w1, acc[0][1], 0, 0, 0);
            acc[1][0] = __builtin_amdgcn_mfma_f32_16x16x32_bf16(a1, w0, acc[1][0], 0, 0, 0);
            acc[1][1] = __builtin_amdgcn_mfma_f32_16x16x32_bf16(a1, w1, acc[1][1], 0, 0, 0);
        }
        __syncthreads();
    }
    float sc = scale ? *scale : 1.0f;
    #pragma unroll
    for (int nf = 0; nf < 2; ++nf) {
        int n = col0 + wn * 32 + nf * 16 + c15;
        float bv = bias ? bias[n] : 0.0f;
        #pragma unroll
        for (int mf = 0; mf < 2; ++mf) {
            #pragma unroll
            for (int r = 0; r < 4; ++r) {
                int m = row0 + wm * 32 + mf * 16 + g * 4 + r;
                float v = acc[mf][nf][r] * sc + bv;
                if (act) v = gelu_exact(v);
                if (res) v += res[(size_t)m * ldo + n];
                if (out_b16) ((unsigned short*)out_)[(size_t)m * ldo + n] = f2b_rne(v);
                else         ((float*)out_)[(size_t)m * ldo + n] = v;
            }
        }
    }
}

// ---------------- prep: K/V slices of src -> K_bf16[h][key][32], VT_bf16[h][32][3072] ----------------
__global__ __launch_bounds__(256) void prep_kv_kernel(const float* __restrict__ src, int ld, int koff, int voff,
                                                      unsigned short* __restrict__ Kb, unsigned short* __restrict__ VTb)
{
    int h = blockIdx.y, k0 = blockIdx.x * 64, t = threadIdx.x;
    __shared__ float tl[64][33];
    #pragma unroll
    for (int it = 0; it < 8; ++it) {
        int idx = t + 256 * it;
        int j = idx >> 5, d = idx & 31;
        Kb[((size_t)h * 3072 + k0 + j) * 32 + d] = f2b_rne(src[(size_t)(k0 + j) * ld + koff + h * 32 + d]);
        tl[j][d] = src[(size_t)(k0 + j) * ld + voff + h * 32 + d];
    }
    __syncthreads();
    #pragma unroll
    for (int it = 0; it < 8; ++it) {
        int idx = t + 256 * it;
        int d = idx >> 6, j = idx & 63;
        VTb[((size_t)h * 32 + d) * 3072 + k0 + j] = f2b_rne(tl[j][d]);
    }
}

// ---------------- split-K MFMA flash attention ----------------
// SPLIT waves per block; wave w handles k-tiles [w*(48/SPLIT), (w+1)*(48/SPLIT)).
// Per-wave barrier-free loop; final LDS combine of (m,l,O-partial). out bf16 [rows][256].
template<int SPLIT>
__global__ __launch_bounds__(64 * SPLIT) void attn_mfma_kernel(
    const float* __restrict__ Q, int ldq,
    const unsigned short* __restrict__ Kb,
    const unsigned short* __restrict__ VTb,
    const unsigned short* __restrict__ biasb,
    unsigned short* __restrict__ out)
{
    constexpr int KT = 48 / SPLIT;
    __shared__ unsigned short P_all[SPLIT * 32 * 72];
    __shared__ float ml[SPLIT * 64];
    const int head = blockIdx.y;
    const int i0 = blockIdx.x * 32;
    const int tid = threadIdx.x;
    const int lane = tid & 63, w = tid >> 6;
    const int c15 = lane & 15, g = lane >> 4;
    unsigned short* P_lds = P_all + w * (32 * 72);
    const unsigned short* Kh  = Kb  + (size_t)head * 3072 * 32;
    const unsigned short* VTh = VTb + (size_t)head * 32 * 3072;
    const f32x4 zf = {0.f, 0.f, 0.f, 0.f};
    const float rs = 0.17677669529663687f;

    short8v qf[2];
    #pragma unroll
    for (int nf = 0; nf < 2; ++nf) {
        const float* qp = Q + (size_t)(i0 + nf * 16 + c15) * ldq + head * 32 + g * 8;
        short8v v;
        #pragma unroll
        for (int j = 0; j < 8; ++j) v[j] = (short)f2b_rne(qp[j]);
        qf[nf] = v;
    }

    float m_[2] = {-1e30f, -1e30f};
    float l_[2] = {0.f, 0.f};
    f32x4 acc[2][2];
    acc[0][0] = zf; acc[0][1] = zf; acc[1][0] = zf; acc[1][1] = zf;

    for (int kt = 0; kt < KT; ++kt) {
        const int k0 = (w * KT + kt) * 64;
        short8v kf[4];
        #pragma unroll
        for (int mf = 0; mf < 4; ++mf)
            kf[mf] = *(const short8v*)(Kh + (size_t)(k0 + mf * 16 + c15) * 32 + g * 8);
        f32x4 s[4][2];
        #pragma unroll
        for (int mf = 0; mf < 4; ++mf)
            #pragma unroll
            for (int nf = 0; nf < 2; ++nf)
                s[mf][nf] = __builtin_amdgcn_mfma_f32_16x16x32_bf16(kf[mf], qf[nf], zf, 0, 0, 0);
        #pragma unroll
        for (int nf = 0; nf < 2; ++nf) {
            const unsigned short* bp = biasb + (size_t)(i0 + nf * 16 + c15) * 3072 + k0;
            #pragma unroll
            for (int mf = 0; mf < 4; ++mf) {
                uint2 bv = *(const uint2*)(bp + mf * 16 + g * 4);
                s[mf][nf][0] = s[mf][nf][0] * rs + __uint_as_float(bv.x << 16);
                s[mf][nf][1] = s[mf][nf][1] * rs + __uint_as_float(bv.x & 0xffff0000u);
                s[mf][nf][2] = s[mf][nf][2] * rs + __uint_as_float(bv.y << 16);
                s[mf][nf][3] = s[mf][nf][3] * rs + __uint_as_float(bv.y & 0xffff0000u);
            }
        }
        #pragma unroll
        for (int nf = 0; nf < 2; ++nf) {
            float tmax = -1e30f;
            #pragma unroll
            for (int mf = 0; mf < 4; ++mf)
                #pragma unroll
                for (int r = 0; r < 4; ++r) tmax = fmaxf(tmax, s[mf][nf][r]);
            tmax = fmaxf(tmax, __shfl_xor(tmax, 16));
            tmax = fmaxf(tmax, __shfl_xor(tmax, 32));
            float mn = fmaxf(m_[nf], tmax);
            float scl = __expf(m_[nf] - mn);
            m_[nf] = mn;
            float ts = 0.f;
            #pragma unroll
            for (int mf = 0; mf < 4; ++mf)
                #pragma unroll
                for (int r = 0; r < 4; ++r) {
                    float p = __expf(s[mf][nf][r] - mn);
                    s[mf][nf][r] = p;
                    ts += p;
                }
            ts += __shfl_xor(ts, 16);
            ts += __shfl_xor(ts, 32);
            l_[nf] = l_[nf] * scl + ts;
            #pragma unroll
            for (int mf = 0; mf < 2; ++mf) {
                acc[mf][nf][0] *= scl; acc[mf][nf][1] *= scl;
                acc[mf][nf][2] *= scl; acc[mf][nf][3] *= scl;
            }
            const int q = nf * 16 + c15;
            #pragma unroll
            for (int mf = 0; mf < 4; ++mf) {
                uint2 pv;
                pv.x = (unsigned)f2b_rne(s[mf][nf][0]) | ((unsigned)f2b_rne(s[mf][nf][1]) << 16);
                pv.y = (unsigned)f2b_rne(s[mf][nf][2]) | ((unsigned)f2b_rne(s[mf][nf][3]) << 16);
                *(uint2*)(P_lds + q * 72 + mf * 16 + g * 4) = pv;
            }
        }
        #pragma unroll
        for (int ks = 0; ks < 2; ++ks) {
            short8v pB[2], vA[2];
            #pragma unroll
            for (int nf = 0; nf < 2; ++nf)
                pB[nf] = *(const short8v*)(P_lds + (nf * 16 + c15) * 72 + ks * 32 + g * 8);
            #pragma unroll
            for (int mf = 0; mf < 2; ++mf)
                vA[mf] = *(const short8v*)(VTh + (size_t)(mf * 16 + c15) * 3072 + k0 + ks * 32 + g * 8);
            #pragma unroll
            for (int mf = 0; mf < 2; ++mf)
                #pragma unroll
                for (int nf = 0; nf < 2; ++nf)
                    acc[mf][nf] = __builtin_amdgcn_mfma_f32_16x16x32_bf16(vA[mf], pB[nf], acc[mf][nf], 0, 0, 0);
        }
    }
    // write partials: O-partial (unnormalized) into own P region reinterpreted as float [32][36]
    float* Olds = (float*)P_all;
    #pragma unroll
    for (int nf = 0; nf < 2; ++nf) {
        int q = nf * 16 + c15;
        #pragma unroll
        for (int mf = 0; mf < 2; ++mf)
            *(f32x4*)(Olds + w * 1152 + q * 36 + mf * 16 + g * 4) = acc[mf][nf];
        if (g == 0) {
            ml[w * 64 + q] = m_[nf];
            ml[w * 64 + 32 + q] = l_[nf];
        }
    }
    __syncthreads();
    if (tid < 256) {
        int q = tid >> 3, d0 = (tid & 7) * 4;
        float M = -1e30f;
        #pragma unroll
        for (int s = 0; s < SPLIT; ++s) M = fmaxf(M, ml[s * 64 + q]);
        float wsv[SPLIT];
        float L = 0.f;
        #pragma unroll
        for (int s = 0; s < SPLIT; ++s) {
            float wv = __expf(ml[s * 64 + q] - M);
            wsv[s] = wv;
            L += wv * ml[s * 64 + 32 + q];
        }
        float invL = 1.0f / L;
        float v0 = 0, v1 = 0, v2 = 0, v3 = 0;
        #pragma unroll
        for (int s = 0; s < SPLIT; ++s) {
            const float* op = Olds + s * 1152 + q * 36 + d0;
            v0 += wsv[s] * op[0]; v1 += wsv[s] * op[1];
            v2 += wsv[s] * op[2]; v3 += wsv[s] * op[3];
        }
        uint2 pk;
        pk.x = (unsigned)f2b_rne(v0 * invL) | ((unsigned)f2b_rne(v1 * invL) << 16);
        pk.y = (unsigned)f2b_rne(v2 * invL) | ((unsigned)f2b_rne(v3 * invL) << 16);
        *(uint2*)(out + (size_t)(i0 + q) * 256 + head * 32 + d0) = pk;
    }
}

extern "C" void kernel_launch(void* const* d_in, const int* in_sizes, int n_in,
                              void* d_out, int out_size, void* d_ws, size_t ws_size,
                              hipStream_t stream)
{
    const float* x        = (const float*)d_in[0];
    const float* C        = (const float*)d_in[1];
    const int*   sidx     = (const int*)d_in[2];
    const unsigned char* mask = (const unsigned char*)d_in[3];
    const float* proj_W   = (const float*)d_in[4];
    const float* proj_b   = (const float*)d_in[5];
    const float* peW      = (const float*)d_in[6];
    const float* peb      = (const float*)d_in[7];
    const float* peg      = (const float*)d_in[8];
    const float* pebt     = (const float*)d_in[9];
    const float* pe_gate  = (const float*)d_in[10];
    const float* alpha_nn = (const float*)d_in[11];
    const float* beta_sn  = (const float*)d_in[12];
    const float* sqW      = (const float*)d_in[13];
    const float* sqb      = (const float*)d_in[14];
    const float* sn_Win   = (const float*)d_in[15];
    const float* sn_bin   = (const float*)d_in[16];
    const float* sn_Wout  = (const float*)d_in[17];
    const float* sn_bout  = (const float*)d_in[18];
    const float* nn_Win   = (const float*)d_in[19];
    const float* nn_bin   = (const float*)d_in[20];
    const float* nn_Wout  = (const float*)d_in[21];
    const float* nn_bout  = (const float*)d_in[22];
    const float* ln_s_g   = (const float*)d_in[23];
    const float* ln_s_b   = (const float*)d_in[24];
    const float* ln_n1_g  = (const float*)d_in[25];
    const float* ln_n1_b  = (const float*)d_in[26];
    const float* ln_n2_g  = (const float*)d_in[27];
    const float* ln_n2_b  = (const float*)d_in[28];
    const float* ffn_W1   = (const float*)d_in[29];
    const float* ffn_b1   = (const float*)d_in[30];
    const float* ffn_W2   = (const float*)d_in[31];
    const float* ffn_b2   = (const float*)d_in[32];
    const float* ffs_W1   = (const float*)d_in[33];
    const float* ffs_b1   = (const float*)d_in[34];
    const float* ffs_W2   = (const float*)d_in[35];
    const float* ffs_b2   = (const float*)d_in[36];
    const float* ln_og    = (const float*)d_in[37];
    const float* ln_ob    = (const float*)d_in[38];

    float* ws = (float*)d_ws;
    float* h       = ws;                                          // 786432
    float* Cn      = ws + 786432;                                 // 786432
    float* sinkq   = ws + 1572864;                                // 65536
    float* maskadd = ws + 1638400;                                // 4096
    unsigned short* hnb    = (unsigned short*)(ws + 1642496);     // 3072x256 bf16
    unsigned short* attnob = (unsigned short*)(ws + 2035712);     // 3072x256 bf16
    unsigned short* sqnb   = (unsigned short*)(ws + 2428928);     // 256x256 bf16
    unsigned short* sgb    = (unsigned short*)(ws + 2461696);     // 256x256 bf16
    unsigned short* Kb     = (unsigned short*)(ws + 2494464);     // 8x3072x32 bf16
    unsigned short* VTb    = (unsigned short*)(ws + 2887680);     // 8x32x3072 bf16
    unsigned short* CTb    = (unsigned short*)(ws + 3280896);     // 256x3072 bf16
    unsigned short* biasb  = (unsigned short*)(ws + 3674112);     // 3072x3072 bf16
    float* big     = ws + 8392704;                                // 2359296 union
    float* q_s   = big;                     // 256x256 f32
    float* kv_s  = big + 65536;             // 3072x512 f32
    float* qkv   = big;                     // 3072x768 f32
    unsigned short* midb = (unsigned short*)big;   // up to 3072x1024 bf16

    dim3 b256(256), b384(384);

    maskadd_kernel<<<12, b256, 0, stream>>>(mask, maskadd);
    node_encode_kernel<<<N_NODES, b256, 0, stream>>>(x, C, mask, proj_W, proj_b, peW, peb, peg, pebt, pe_gate, h);
    gather_b16_kernel<<<S_SINK, b256, 0, stream>>>(h, sidx, sgb);
    gemm_mfma_kernel<<<dim3(4, 4), b256, 0, stream>>>(sgb, 256, 0, sqW, 256, 1, sqb, nullptr, nullptr, sinkq, 256, 0, 256, 0);
    cn_kernel<<<N_NODES, b256, 0, stream>>>(C, Cn);
    transpose_b16_kernel<<<dim3(96, 8), b256, 0, stream>>>(C, beta_sn, maskadd, CTb);
    gemm_mfma_kernel<<<dim3(48, 48), b256, 0, stream>>>(Cn, 256, 1, Cn, 256, 1, maskadd, nullptr, alpha_nn, biasb, 3072, 1, 256, 0);

    for (int l = 0; l < 3; ++l) {
        const float* Win_s  = sn_Win  + (size_t)l * 768 * 256;
        const float* bin_s  = sn_bin  + l * 768;
        const float* Wout_s = sn_Wout + (size_t)l * 256 * 256;
        const float* bout_s = sn_bout + l * 256;
        const float* Win_n  = nn_Win  + (size_t)l * 768 * 256;
        const float* bin_n  = nn_bin  + l * 768;
        const float* Wout_n = nn_Wout + (size_t)l * 256 * 256;
        const float* bout_n = nn_bout + l * 256;

        // ---- sink branch ----
        ln_b16_kernel<<<S_SINK, b256, 0, stream>>>(sinkq, ln_s_g + l * 256, ln_s_b + l * 256, sqnb);
        gemm_mfma_kernel<<<dim3(4, 4), b256, 0, stream>>>(sqnb, 256, 0, Win_s, 256, 1, bin_s, nullptr, nullptr, q_s, 256, 0, 256, 0);
        gemm_mfma_kernel<<<dim3(8, 48), b256, 0, stream>>>(h, 256, 1, Win_s + 256 * 256, 256, 1, bin_s + 256, nullptr, nullptr, kv_s, 512, 0, 256, 0);
        prep_kv_kernel<<<dim3(48, 8), b256, 0, stream>>>(kv_s, 512, 0, 256, Kb, VTb);
        attn_mfma_kernel<6><<<dim3(8, 8), b384, 0, stream>>>(q_s, 256, Kb, VTb, CTb, attnob);
        gemm_mfma_kernel<<<dim3(4, 4), b256, 0, stream>>>(attnob, 256, 0, Wout_s, 256, 1, bout_s, sinkq, nullptr, sinkq, 256, 0, 256, 0);
        gemm_mfma_kernel<<<dim3(16, 4), b256, 0, stream>>>(sinkq, 256, 1, ffs_W1 + (size_t)l * 262144, 256, 1, ffs_b1 + l * 1024, nullptr, nullptr, midb, 1024, 1, 256, 1);
        gemm_mfma_kernel<<<dim3(4, 4), b256, 0, stream>>>(midb, 1024, 0, ffs_W2 + (size_t)l * 262144, 1024, 1, ffs_b2 + l * 256, sinkq, nullptr, sinkq, 256, 0, 1024, 0);

        // ---- node branch ----
        ln_b16_kernel<<<N_NODES, b256, 0, stream>>>(h, ln_n1_g + l * 256, ln_n1_b + l * 256, hnb);
        gemm_mfma_kernel<<<dim3(12, 48), b256, 0, stream>>>(hnb, 256, 0, Win_n, 256, 1, bin_n, nullptr, nullptr, qkv, 768, 0, 256, 0);
        prep_kv_kernel<<<dim3(48, 8), b256, 0, stream>>>(qkv, 768, 256, 512, Kb, VTb);
        attn_mfma_kernel<6><<<dim3(96, 8), b384, 0, stream>>>(qkv, 768, Kb, VTb, biasb, attnob);
        gemm_mfma_kernel<<<dim3(4, 48), b256, 0, stream>>>(attnob, 256, 0, Wout_n, 256, 1, bout_n, h, nullptr, h, 256, 0, 256, 0);
        ln_b16_kernel<<<N_NODES, b256, 0, stream>>>(h, ln_n2_g + l * 256, ln_n2_b + l * 256, hnb);
        gemm_mfma_kernel<<<dim3(16, 48), b256, 0, stream>>>(hnb, 256, 0, ffn_W1 + (size_t)l * 262144, 256, 1, ffn_b1 + l * 1024, nullptr, nullptr, midb, 1024, 1, 256, 1);
        gemm_mfma_kernel<<<dim3(4, 48), b256, 0, stream>>>(midb, 1024, 0, ffn_W2 + (size_t)l * 262144, 1024, 1, ffn_b2 + l * 256, h, nullptr, h, 256, 0, 1024, 0);
    }

    ln_out_kernel<<<S_SINK, b256, 0, stream>>>(sinkq, ln_og, ln_ob, (float*)d_out);
}

// Round 5
// 754.294 us; speedup vs baseline: 11.0200x; 1.0196x over previous
//
#include <hip/hip_runtime.h>
#include <hip/hip_bf16.h>

#define N_NODES 3072
#define S_SINK  256
#define DIN     64

typedef __attribute__((ext_vector_type(8))) short short8v;
typedef __attribute__((ext_vector_type(4))) float f32x4;

#define LOG2E 1.4426950408889634f

#if defined(__has_builtin)
#if __has_builtin(__builtin_amdgcn_exp2f)
#define EXP2(x) __builtin_amdgcn_exp2f(x)
#else
#define EXP2(x) exp2f(x)
#endif
#else
#define EXP2(x) exp2f(x)
#endif

static __device__ __forceinline__ float gelu_exact(float v) {
    return 0.5f * v * (1.0f + erff(v * 0.70710678118654752f));
}
static __device__ __forceinline__ unsigned short f2b_rne(float f) {
    unsigned int b = __float_as_uint(f);
    b += 0x7fffu + ((b >> 16) & 1u);
    return (unsigned short)(b >> 16);
}

// ---------------- f32 -> bf16 bulk convert ----------------
__global__ __launch_bounds__(256) void cvt_b16_kernel(const float* __restrict__ src,
                                                      unsigned short* __restrict__ dst, int n) {
    int i = (blockIdx.x * 256 + threadIdx.x) * 4;
    if (i >= n) return;
    float4 v = *(const float4*)(src + i);
    uint2 o;
    o.x = (unsigned)f2b_rne(v.x) | ((unsigned)f2b_rne(v.y) << 16);
    o.y = (unsigned)f2b_rne(v.z) | ((unsigned)f2b_rne(v.w) << 16);
    *(uint2*)(dst + i) = o;
}

// ---------------- node encode: h = x@Wp.T + b + pe ----------------
__global__ __launch_bounds__(256) void node_encode_kernel(
    const float* __restrict__ x, const float* __restrict__ C,
    const unsigned char* __restrict__ mask,
    const float* __restrict__ Wp, const float* __restrict__ bp,
    const float* __restrict__ peW, const float* __restrict__ peb,
    const float* __restrict__ peg, const float* __restrict__ pebt,
    const float* __restrict__ gate,
    float* __restrict__ h)
{
    int i = blockIdx.x, t = threadIdx.x;
    __shared__ float xs[DIN];
    __shared__ float r1[256], r2[256];
    __shared__ float zs[20];
    if (t < DIN) xs[t] = x[i * DIN + t];
    float c  = C[i * 256 + t];
    float cc = fminf(fmaxf(c, 0.0f), 1.0f);
    r1[t] = cc; r2[t] = cc * cc;
    __syncthreads();
    for (int s = 128; s > 0; s >>= 1) { if (t < s) { r1[t] += r1[t + s]; r2[t] += r2[t + s]; } __syncthreads(); }
    float cm  = r1[0] * (1.0f / 256.0f);
    float cms = r2[0] * (1.0f / 256.0f);
    __syncthreads();
    r1[t] = cc; r2[t] = cc;
    __syncthreads();
    for (int s = 128; s > 0; s >>= 1) { if (t < s) { r1[t] = fmaxf(r1[t], r1[t + s]); r2[t] = fminf(r2[t], r2[t + s]); } __syncthreads(); }
    float cmax = r1[0], cmin = r2[0];
    __syncthreads();
    if (t == 0) {
        float var  = fmaxf(cms - cm * cm, 0.0f);
        float cstd = sqrtf(var);
        zs[0] = cm; zs[1] = cmax; zs[2] = cmin; zs[3] = cstd;
        float w = 0.15f + 1e-6f;
        for (int k = 0; k < 8; ++k) {
            float ck = (float)k / 7.0f;
            float d1 = (cm   - ck) / w;
            float d2 = (cmax - ck) / w;
            zs[4 + k]  = expf(-0.5f * d1 * d1);
            zs[12 + k] = expf(-0.5f * d2 * d2);
        }
    }
    __syncthreads();
    float pl = peb[t];
    #pragma unroll
    for (int f = 0; f < 20; ++f) pl += zs[f] * peW[t * 20 + f];
    r1[t] = pl; r2[t] = pl * pl;
    __syncthreads();
    for (int s = 128; s > 0; s >>= 1) { if (t < s) { r1[t] += r1[t + s]; r2[t] += r2[t + s]; } __syncthreads(); }
    float m  = r1[0] * (1.0f / 256.0f);
    float vv = fmaxf(r2[0] * (1.0f / 256.0f) - m * m, 0.0f);
    float pe = (pl - m) * rsqrtf(vv + 1e-5f) * peg[t] + pebt[t];
    pe *= gate[0];
    if (mask[i] != 0) pe = 0.0f;
    float hv = bp[t];
    #pragma unroll
    for (int k = 0; k < DIN; ++k) hv += xs[k] * Wp[t * DIN + k];
    h[(size_t)i * 256 + t] = hv + pe;
}

// ---------------- Cnb = bf16(C / (||C||+1e-6)) ----------------
__global__ __launch_bounds__(256) void cn_kernel(const float* __restrict__ C, unsigned short* __restrict__ Cnb) {
    int i = blockIdx.x, t = threadIdx.x;
    __shared__ float r1[256];
    float v = C[(size_t)i * 256 + t];
    r1[t] = v * v;
    __syncthreads();
    for (int s = 128; s > 0; s >>= 1) { if (t < s) r1[t] += r1[t + s]; __syncthreads(); }
    float nrm = sqrtf(r1[0]) + 1e-6f;
    Cnb[(size_t)i * 256 + t] = f2b_rne(v / nrm);
}

// ---------------- maskadd[j] = -10000 * log2e * mask[j] (log2 domain) ----------------
__global__ __launch_bounds__(256) void maskadd_kernel(const unsigned char* __restrict__ mask, float* __restrict__ ma) {
    int j = blockIdx.x * 256 + threadIdx.x;
    if (j < N_NODES) ma[j] = -10000.0f * LOG2E * (float)mask[j];
}

// ---------------- CTb[s][j] = bf16(log2e*beta*C[j][s] + maskadd[j]) ----------------
__global__ __launch_bounds__(256) void transpose_b16_kernel(const float* __restrict__ C, const float* __restrict__ beta,
                                                            const float* __restrict__ maskadd, unsigned short* __restrict__ CTb) {
    __shared__ float tile[32][33];
    int bx = blockIdx.x * 32;              // node dim
    int by = blockIdx.y * 32;              // sink dim
    int tx = threadIdx.x & 31, ty = threadIdx.x >> 5;
    float bt = beta[0] * LOG2E;
    #pragma unroll
    for (int r = 0; r < 4; ++r) {
        int row = bx + ty + r * 8;
        tile[ty + r * 8][tx] = C[(size_t)row * 256 + by + tx];
    }
    __syncthreads();
    #pragma unroll
    for (int r = 0; r < 4; ++r) {
        int srow = by + ty + r * 8;
        CTb[(size_t)srow * 3072 + bx + tx] = f2b_rne(bt * tile[tx][ty + r * 8] + maskadd[bx + tx]);
    }
}

// ---------------- gather rows -> bf16 ----------------
__global__ __launch_bounds__(256) void gather_b16_kernel(const float* __restrict__ h, const int* __restrict__ idx,
                                                         unsigned short* __restrict__ sg) {
    int s = blockIdx.x, t = threadIdx.x;
    sg[(size_t)s * 256 + t] = f2b_rne(h[(size_t)idx[s] * 256 + t]);
}

// ---------------- LayerNorm over 256 channels -> bf16 ----------------
__global__ __launch_bounds__(256) void ln_b16_kernel(const float* __restrict__ in, const float* __restrict__ g,
                                                     const float* __restrict__ b, unsigned short* __restrict__ out) {
    int i = blockIdx.x, t = threadIdx.x;
    __shared__ float r1[256], r2[256];
    float v = in[(size_t)i * 256 + t];
    r1[t] = v; r2[t] = v * v;
    __syncthreads();
    for (int s = 128; s > 0; s >>= 1) { if (t < s) { r1[t] += r1[t + s]; r2[t] += r2[t + s]; } __syncthreads(); }
    float m  = r1[0] * (1.0f / 256.0f);
    float vv = fmaxf(r2[0] * (1.0f / 256.0f) - m * m, 0.0f);
    out[(size_t)i * 256 + t] = f2b_rne((v - m) * rsqrtf(vv + 1e-5f) * g[t] + b[t]);
}

// final LN -> d_out as float32
__global__ __launch_bounds__(256) void ln_out_kernel(const float* __restrict__ in, const float* __restrict__ g,
                                                     const float* __restrict__ b, float* __restrict__ out) {
    int i = blockIdx.x, t = threadIdx.x;
    __shared__ float r1[256], r2[256];
    float v = in[(size_t)i * 256 + t];
    r1[t] = v; r2[t] = v * v;
    __syncthreads();
    for (int s = 128; s > 0; s >>= 1) { if (t < s) { r1[t] += r1[t + s]; r2[t] += r2[t + s]; } __syncthreads(); }
    float m  = r1[0] * (1.0f / 256.0f);
    float vv = fmaxf(r2[0] * (1.0f / 256.0f) - m * m, 0.0f);
    out[(size_t)i * 256 + t] = (v - m) * rsqrtf(vv + 1e-5f) * g[t] + b[t];
}

// ---------------- staging load helper: 8 elems -> bf16x8 ----------------
static __device__ __forceinline__ short8v ld8_cvt(const void* base, size_t off, int isf32) {
    if (isf32) {
        const float* p = (const float*)base + off;
        float4 a = *(const float4*)p;
        float4 b = *(const float4*)(p + 4);
        short8v v;
        v[0] = (short)f2b_rne(a.x); v[1] = (short)f2b_rne(a.y);
        v[2] = (short)f2b_rne(a.z); v[3] = (short)f2b_rne(a.w);
        v[4] = (short)f2b_rne(b.x); v[5] = (short)f2b_rne(b.y);
        v[6] = (short)f2b_rne(b.z); v[7] = (short)f2b_rne(b.w);
        return v;
    }
    return *(const short8v*)((const unsigned short*)base + off);
}

// ---------------- MFMA GEMM: out = epi((scale*scmul)*(A@W^T) + bias) [+res] ----------------
__global__ __launch_bounds__(256) void gemm_mfma_kernel(
    const void* __restrict__ A_, int lda, int af32,
    const void* __restrict__ W_, int ldw, int wf32,
    const float* __restrict__ bias,
    const float* __restrict__ res,
    const float* __restrict__ scale, float scmul,
    void* __restrict__ out_, int ldo, int out_b16,
    int K, int act)
{
    __shared__ unsigned short As[64][72];
    __shared__ unsigned short Ws[64][72];
    int tid = threadIdx.x;
    int lane = tid & 63, wid = tid >> 6;
    int c15 = lane & 15, g = lane >> 4;
    int wm = wid & 1, wn = wid >> 1;
    int row0 = blockIdx.y * 64, col0 = blockIdx.x * 64;
    f32x4 acc[2][2];
    const f32x4 zf = {0.f, 0.f, 0.f, 0.f};
    acc[0][0] = zf; acc[0][1] = zf; acc[1][0] = zf; acc[1][1] = zf;

    for (int k0 = 0; k0 < K; k0 += 64) {
        #pragma unroll
        for (int hh = 0; hh < 2; ++hh) {
            int cid = tid + hh * 256;
            int rr = cid >> 3, cc = (cid & 7) * 8;
            short8v va = ld8_cvt(A_, (size_t)(row0 + rr) * lda + k0 + cc, af32);
            short8v vw = ld8_cvt(W_, (size_t)(col0 + rr) * ldw + k0 + cc, wf32);
            *(short8v*)(&As[rr][cc]) = va;
            *(short8v*)(&Ws[rr][cc]) = vw;
        }
        __syncthreads();
        #pragma unroll
        for (int ks = 0; ks < 2; ++ks) {
            short8v a0 = *(const short8v*)(&As[wm * 32 + c15][ks * 32 + g * 8]);
            short8v a1 = *(const short8v*)(&As[wm * 32 + 16 + c15][ks * 32 + g * 8]);
            short8v w0 = *(const short8v*)(&Ws[wn * 32 + c15][ks * 32 + g * 8]);
            short8v w1 = *(const short8v*)(&Ws[wn * 32 + 16 + c15][ks * 32 + g * 8]);
            acc[0][0] = __builtin_amdgcn_mfma_f32_16x16x32_bf16(a0, w0, acc[0][0], 0, 0, 0);
            acc[0][1] = __builtin_amdgcn_mfma_f32_16x16x32_bf16(a0, w1, acc[0][1], 0, 0, 0);
            acc[1][0] = __builtin_amdgcn_mfma_f32_16x16x32_bf16(a1, w0, acc[1][0], 0, 0, 0);
            acc[1][1] = __builtin_amdgcn_mfma_f32_16x16x32_bf16(a1, w1, acc[1][1], 0, 0, 0);
        }
        __syncthreads();
    }
    float sc = (scale ? *scale : 1.0f) * scmul;
    #pragma unroll
    for (int nf = 0; nf < 2; ++nf) {
        int n = col0 + wn * 32 + nf * 16 + c15;
        float bv = bias ? bias[n] : 0.0f;
        #pragma unroll
        for (int mf = 0; mf < 2; ++mf) {
            #pragma unroll
            for (int r = 0; r < 4; ++r) {
                int m = row0 + wm * 32 + mf * 16 + g * 4 + r;
                float v = acc[mf][nf][r] * sc + bv;
                if (act) v = gelu_exact(v);
                if (res) v += res[(size_t)m * ldo + n];
                if (out_b16) ((unsigned short*)out_)[(size_t)m * ldo + n] = f2b_rne(v);
                else         ((float*)out_)[(size_t)m * ldo + n] = v;
            }
        }
    }
}

// ---------------- prep: V slice (bf16 src) -> VT_bf16[h][32][3072] ----------------
__global__ __launch_bounds__(256) void prep_vt_kernel(const unsigned short* __restrict__ src, int ld, int voff,
                                                      unsigned short* __restrict__ VTb)
{
    int h = blockIdx.y, k0 = blockIdx.x * 64, t = threadIdx.x;
    __shared__ unsigned short tl[64][33];
    #pragma unroll
    for (int it = 0; it < 8; ++it) {
        int idx = t + 256 * it;
        int j = idx >> 5, d = idx & 31;
        tl[j][d] = src[(size_t)(k0 + j) * ld + voff + h * 32 + d];
    }
    __syncthreads();
    #pragma unroll
    for (int it = 0; it < 8; ++it) {
        int idx = t + 256 * it;
        int d = idx >> 6, j = idx & 63;
        VTb[((size_t)h * 32 + d) * 3072 + k0 + j] = tl[j][d];
    }
}

// ---------------- split-K MFMA flash attention, log2 domain, prefetched ----------------
// scores_log2 = (K.Q)*rs*log2e + bias_log2;  p = 2^(s - m);  defer-max threshold 8.
template<int SPLIT>
__global__ __launch_bounds__(64 * SPLIT) void attn_mfma_kernel(
    const unsigned short* __restrict__ Qb, int ldq,
    const unsigned short* __restrict__ Ksrc, int ldk,
    const unsigned short* __restrict__ VTb,
    const unsigned short* __restrict__ biasb,
    unsigned short* __restrict__ out)
{
    constexpr int KT = 48 / SPLIT;
    __shared__ unsigned short P_all[SPLIT * 32 * 72];
    __shared__ float ml[SPLIT * 64];
    const int head = blockIdx.y;
    const int i0 = blockIdx.x * 32;
    const int tid = threadIdx.x;
    const int lane = tid & 63, w = tid >> 6;
    const int c15 = lane & 15, g = lane >> 4;
    unsigned short* P_lds = P_all + w * (32 * 72);
    const unsigned short* Kh  = Ksrc + (size_t)head * 32;
    const unsigned short* VTh = VTb + (size_t)head * 32 * 3072;
    const f32x4 zf = {0.f, 0.f, 0.f, 0.f};
    const float rsl2 = 0.25503164113124427f;   // log2(e)/sqrt(32)

    short8v qf[2];
    #pragma unroll
    for (int nf = 0; nf < 2; ++nf)
        qf[nf] = *(const short8v*)(Qb + (size_t)(i0 + nf * 16 + c15) * ldq + head * 32 + g * 8);

    float m_[2] = {-1e30f, -1e30f};
    float l_[2] = {0.f, 0.f};
    f32x4 acc[2][2];
    acc[0][0] = zf; acc[0][1] = zf; acc[1][0] = zf; acc[1][1] = zf;
    const int kbase = w * KT * 64;

    auto LOADT = [&](short8v (&kf)[4], uint2 (&bv)[2][4], int k0) {
        #pragma unroll
        for (int mf = 0; mf < 4; ++mf)
            kf[mf] = *(const short8v*)(Kh + (size_t)(k0 + mf * 16 + c15) * ldk + g * 8);
        #pragma unroll
        for (int nf = 0; nf < 2; ++nf) {
            const unsigned short* bp = biasb + (size_t)(i0 + nf * 16 + c15) * 3072 + k0;
            #pragma unroll
            for (int mf = 0; mf < 4; ++mf)
                bv[nf][mf] = *(const uint2*)(bp + mf * 16 + g * 4);
        }
    };

    auto COMPUTE = [&](short8v (&kf)[4], uint2 (&bv)[2][4], int k0) {
        #pragma unroll
        for (int nf = 0; nf < 2; ++nf) {
            f32x4 s[4];
            __builtin_amdgcn_s_setprio(1);
            #pragma unroll
            for (int mf = 0; mf < 4; ++mf)
                s[mf] = __builtin_amdgcn_mfma_f32_16x16x32_bf16(kf[mf], qf[nf], zf, 0, 0, 0);
            __builtin_amdgcn_s_setprio(0);
            #pragma unroll
            for (int mf = 0; mf < 4; ++mf) {
                uint2 b = bv[nf][mf];
                s[mf][0] = s[mf][0] * rsl2 + __uint_as_float(b.x << 16);
                s[mf][1] = s[mf][1] * rsl2 + __uint_as_float(b.x & 0xffff0000u);
                s[mf][2] = s[mf][2] * rsl2 + __uint_as_float(b.y << 16);
                s[mf][3] = s[mf][3] * rsl2 + __uint_as_float(b.y & 0xffff0000u);
            }
            float t01 = fmaxf(fmaxf(s[0][0], s[0][1]), fmaxf(s[0][2], s[0][3]));
            float t23 = fmaxf(fmaxf(s[1][0], s[1][1]), fmaxf(s[1][2], s[1][3]));
            float t45 = fmaxf(fmaxf(s[2][0], s[2][1]), fmaxf(s[2][2], s[2][3]));
            float t67 = fmaxf(fmaxf(s[3][0], s[3][1]), fmaxf(s[3][2], s[3][3]));
            float tmax = fmaxf(fmaxf(t01, t23), fmaxf(t45, t67));
            tmax = fmaxf(tmax, __shfl_xor(tmax, 16));
            tmax = fmaxf(tmax, __shfl_xor(tmax, 32));
            if (!__all(tmax <= m_[nf] + 8.0f)) {       // defer-max (T13)
                float mn = fmaxf(m_[nf], tmax);
                float scl = EXP2(m_[nf] - mn);
                m_[nf] = mn;
                l_[nf] *= scl;
                #pragma unroll
                for (int mf = 0; mf < 2; ++mf) {
                    acc[mf][nf][0] *= scl; acc[mf][nf][1] *= scl;
                    acc[mf][nf][2] *= scl; acc[mf][nf][3] *= scl;
                }
            }
            float mcur = m_[nf];
            float ts = 0.f;
            #pragma unroll
            for (int mf = 0; mf < 4; ++mf) {
                #pragma unroll
                for (int r = 0; r < 4; ++r) {
                    float p = EXP2(s[mf][r] - mcur);
                    s[mf][r] = p;
                    ts += p;
                }
            }
            ts += __shfl_xor(ts, 16);
            ts += __shfl_xor(ts, 32);
            l_[nf] += ts;
            const int q = nf * 16 + c15;
            #pragma unroll
            for (int mf = 0; mf < 4; ++mf) {
                uint2 pv;
                pv.x = (unsigned)f2b_rne(s[mf][0]) | ((unsigned)f2b_rne(s[mf][1]) << 16);
                pv.y = (unsigned)f2b_rne(s[mf][2]) | ((unsigned)f2b_rne(s[mf][3]) << 16);
                *(uint2*)(P_lds + q * 72 + mf * 16 + g * 4) = pv;
            }
        }
        #pragma unroll
        for (int ks = 0; ks < 2; ++ks) {
            short8v pB[2], vA[2];
            #pragma unroll
            for (int nf = 0; nf < 2; ++nf)
                pB[nf] = *(const short8v*)(P_lds + (nf * 16 + c15) * 72 + ks * 32 + g * 8);
            #pragma unroll
            for (int mf = 0; mf < 2; ++mf)
                vA[mf] = *(const short8v*)(VTh + (size_t)(mf * 16 + c15) * 3072 + k0 + ks * 32 + g * 8);
            __builtin_amdgcn_s_setprio(1);
            #pragma unroll
            for (int mf = 0; mf < 2; ++mf)
                #pragma unroll
                for (int nf = 0; nf < 2; ++nf)
                    acc[mf][nf] = __builtin_amdgcn_mfma_f32_16x16x32_bf16(vA[mf], pB[nf], acc[mf][nf], 0, 0, 0);
            __builtin_amdgcn_s_setprio(0);
        }
    };

    short8v kfA[4], kfB[4];
    uint2 bvA[2][4], bvB[2][4];
    LOADT(kfA, bvA, kbase);
    for (int kt = 0; kt < KT; kt += 2) {
        LOADT(kfB, bvB, kbase + (kt + 1) * 64);           // prefetch t+1
        COMPUTE(kfA, bvA, kbase + kt * 64);
        if (kt + 2 < KT) LOADT(kfA, bvA, kbase + (kt + 2) * 64);  // prefetch t+2
        COMPUTE(kfB, bvB, kbase + (kt + 1) * 64);
    }

    // write partials: O-partial into P region reinterpreted as float [SPLIT][32][36]
    float* Olds = (float*)P_all;
    #pragma unroll
    for (int nf = 0; nf < 2; ++nf) {
        int q = nf * 16 + c15;
        #pragma unroll
        for (int mf = 0; mf < 2; ++mf)
            *(f32x4*)(Olds + w * 1152 + q * 36 + mf * 16 + g * 4) = acc[mf][nf];
        if (g == 0) {
            ml[w * 64 + q] = m_[nf];
            ml[w * 64 + 32 + q] = l_[nf];
        }
    }
    __syncthreads();
    if (tid < 256) {
        int q = tid >> 3, d0 = (tid & 7) * 4;
        float M = -1e30f;
        #pragma unroll
        for (int s = 0; s < SPLIT; ++s) M = fmaxf(M, ml[s * 64 + q]);
        float wsv[SPLIT];
        float L = 0.f;
        #pragma unroll
        for (int s = 0; s < SPLIT; ++s) {
            float wv = EXP2(ml[s * 64 + q] - M);
            wsv[s] = wv;
            L += wv * ml[s * 64 + 32 + q];
        }
        float invL = 1.0f / L;
        float v0 = 0, v1 = 0, v2 = 0, v3 = 0;
        #pragma unroll
        for (int s = 0; s < SPLIT; ++s) {
            const float* op = Olds + s * 1152 + q * 36 + d0;
            v0 += wsv[s] * op[0]; v1 += wsv[s] * op[1];
            v2 += wsv[s] * op[2]; v3 += wsv[s] * op[3];
        }
        uint2 pk;
        pk.x = (unsigned)f2b_rne(v0 * invL) | ((unsigned)f2b_rne(v1 * invL) << 16);
        pk.y = (unsigned)f2b_rne(v2 * invL) | ((unsigned)f2b_rne(v3 * invL) << 16);
        *(uint2*)(out + (size_t)(i0 + q) * 256 + head * 32 + d0) = pk;
    }
}

extern "C" void kernel_launch(void* const* d_in, const int* in_sizes, int n_in,
                              void* d_out, int out_size, void* d_ws, size_t ws_size,
                              hipStream_t stream)
{
    const float* x        = (const float*)d_in[0];
    const float* C        = (const float*)d_in[1];
    const int*   sidx     = (const int*)d_in[2];
    const unsigned char* mask = (const unsigned char*)d_in[3];
    const float* proj_W   = (const float*)d_in[4];
    const float* proj_b   = (const float*)d_in[5];
    const float* peW      = (const float*)d_in[6];
    const float* peb      = (const float*)d_in[7];
    const float* peg      = (const float*)d_in[8];
    const float* pebt     = (const float*)d_in[9];
    const float* pe_gate  = (const float*)d_in[10];
    const float* alpha_nn = (const float*)d_in[11];
    const float* beta_sn  = (const float*)d_in[12];
    const float* sqW      = (const float*)d_in[13];
    const float* sqb      = (const float*)d_in[14];
    const float* sn_Win   = (const float*)d_in[15];
    const float* sn_bin   = (const float*)d_in[16];
    const float* sn_Wout  = (const float*)d_in[17];
    const float* sn_bout  = (const float*)d_in[18];
    const float* nn_Win   = (const float*)d_in[19];
    const float* nn_bin   = (const float*)d_in[20];
    const float* nn_Wout  = (const float*)d_in[21];
    const float* nn_bout  = (const float*)d_in[22];
    const float* ln_s_g   = (const float*)d_in[23];
    const float* ln_s_b   = (const float*)d_in[24];
    const float* ln_n1_g  = (const float*)d_in[25];
    const float* ln_n1_b  = (const float*)d_in[26];
    const float* ln_n2_g  = (const float*)d_in[27];
    const float* ln_n2_b  = (const float*)d_in[28];
    const float* ffn_W1   = (const float*)d_in[29];
    const float* ffn_b1   = (const float*)d_in[30];
    const float* ffn_W2   = (const float*)d_in[31];
    const float* ffn_b2   = (const float*)d_in[32];
    const float* ffs_W1   = (const float*)d_in[33];
    const float* ffs_b1   = (const float*)d_in[34];
    const float* ffs_W2   = (const float*)d_in[35];
    const float* ffs_b2   = (const float*)d_in[36];
    const float* ln_og    = (const float*)d_in[37];
    const float* ln_ob    = (const float*)d_in[38];

    float* ws = (float*)d_ws;
    float* h       = ws;                                          // 786432
    float* sinkq   = ws + 786432;                                 // 65536
    float* maskadd = ws + 851968;                                 // 4096
    unsigned short* Cnb    = (unsigned short*)(ws + 856064);      // 3072x256
    unsigned short* hnb    = (unsigned short*)(ws + 1249280);     // 3072x256
    unsigned short* attnob = (unsigned short*)(ws + 1642496);     // 3072x256
    unsigned short* sqnb   = (unsigned short*)(ws + 2035712);     // 256x256
    unsigned short* sgb    = (unsigned short*)(ws + 2068480);     // 256x256
    unsigned short* VTb    = (unsigned short*)(ws + 2101248);     // 8x32x3072
    unsigned short* CTb    = (unsigned short*)(ws + 2494464);     // 256x3072
    unsigned short* biasb  = (unsigned short*)(ws + 2887680);     // 3072x3072
    unsigned short* wb     = (unsigned short*)(ws + 7606272);     // weights bf16 pool (4784128)
    float* big     = ws + 9998336;                                // 1572864 union
    // weight pool offsets (ushorts)
    unsigned short* sqWb    = wb;
    unsigned short* snWinb  = wb + 65536;
    unsigned short* snWoutb = wb + 655360;
    unsigned short* nnWinb  = wb + 851968;
    unsigned short* nnWoutb = wb + 1441792;
    unsigned short* ffnW1b  = wb + 1638400;
    unsigned short* ffnW2b  = wb + 2424832;
    unsigned short* ffsW1b  = wb + 3211264;
    unsigned short* ffsW2b  = wb + 3997696;
    // big union: sink {q_sb, kv_sb, mid_sb} / node {qkvb} then {midb}
    unsigned short* q_sb  = (unsigned short*)big;                 // 256x256
    unsigned short* kv_sb = (unsigned short*)(big + 32768);       // 3072x512
    unsigned short* mid_sb= (unsigned short*)(big + 819200);      // 256x1024
    unsigned short* qkvb  = (unsigned short*)big;                 // 3072x768
    unsigned short* midb  = (unsigned short*)big;                 // 3072x1024 (after qkv dead)

    dim3 b256(256), b384(384);

    // one-time weight conversion to bf16
    cvt_b16_kernel<<<64,   b256, 0, stream>>>(sqW,     sqWb,    65536);
    cvt_b16_kernel<<<576,  b256, 0, stream>>>(sn_Win,  snWinb,  589824);
    cvt_b16_kernel<<<192,  b256, 0, stream>>>(sn_Wout, snWoutb, 196608);
    cvt_b16_kernel<<<576,  b256, 0, stream>>>(nn_Win,  nnWinb,  589824);
    cvt_b16_kernel<<<192,  b256, 0, stream>>>(nn_Wout, nnWoutb, 196608);
    cvt_b16_kernel<<<768,  b256, 0, stream>>>(ffn_W1,  ffnW1b,  786432);
    cvt_b16_kernel<<<768,  b256, 0, stream>>>(ffn_W2,  ffnW2b,  786432);
    cvt_b16_kernel<<<768,  b256, 0, stream>>>(ffs_W1,  ffsW1b,  786432);
    cvt_b16_kernel<<<768,  b256, 0, stream>>>(ffs_W2,  ffsW2b,  786432);

    maskadd_kernel<<<12, b256, 0, stream>>>(mask, maskadd);
    node_encode_kernel<<<N_NODES, b256, 0, stream>>>(x, C, mask, proj_W, proj_b, peW, peb, peg, pebt, pe_gate, h);
    gather_b16_kernel<<<S_SINK, b256, 0, stream>>>(h, sidx, sgb);
    gemm_mfma_kernel<<<dim3(4, 4), b256, 0, stream>>>(sgb, 256, 0, sqWb, 256, 0, sqb, nullptr, nullptr, 1.0f, sinkq, 256, 0, 256, 0);
    cn_kernel<<<N_NODES, b256, 0, stream>>>(C, Cnb);
    transpose_b16_kernel<<<dim3(96, 8), b256, 0, stream>>>(C, beta_sn, maskadd, CTb);
    gemm_mfma_kernel<<<dim3(48, 48), b256, 0, stream>>>(Cnb, 256, 0, Cnb, 256, 0, maskadd, nullptr, alpha_nn, LOG2E, biasb, 3072, 1, 256, 0);

    for (int l = 0; l < 3; ++l) {
        // ---- sink branch ----
        ln_b16_kernel<<<S_SINK, b256, 0, stream>>>(sinkq, ln_s_g + l * 256, ln_s_b + l * 256, sqnb);
        gemm_mfma_kernel<<<dim3(4, 4), b256, 0, stream>>>(sqnb, 256, 0, snWinb + (size_t)l * 196608, 256, 0, sn_bin + l * 768, nullptr, nullptr, 1.0f, q_sb, 256, 1, 256, 0);
        gemm_mfma_kernel<<<dim3(8, 48), b256, 0, stream>>>(h, 256, 1, snWinb + (size_t)l * 196608 + 65536, 256, 0, sn_bin + l * 768 + 256, nullptr, nullptr, 1.0f, kv_sb, 512, 1, 256, 0);
        prep_vt_kernel<<<dim3(48, 8), b256, 0, stream>>>(kv_sb, 512, 256, VTb);
        attn_mfma_kernel<6><<<dim3(8, 8), b384, 0, stream>>>(q_sb, 256, kv_sb, 512, VTb, CTb, attnob);
        gemm_mfma_kernel<<<dim3(4, 4), b256, 0, stream>>>(attnob, 256, 0, snWoutb + (size_t)l * 65536, 256, 0, sn_bout + l * 256, sinkq, nullptr, 1.0f, sinkq, 256, 0, 256, 0);
        gemm_mfma_kernel<<<dim3(16, 4), b256, 0, stream>>>(sinkq, 256, 1, ffsW1b + (size_t)l * 262144, 256, 0, ffs_b1 + l * 1024, nullptr, nullptr, 1.0f, mid_sb, 1024, 1, 256, 1);
        gemm_mfma_kernel<<<dim3(4, 4), b256, 0, stream>>>(mid_sb, 1024, 0, ffsW2b + (size_t)l * 262144, 1024, 0, ffs_b2 + l * 256, sinkq, nullptr, 1.0f, sinkq, 256, 0, 1024, 0);

        // ---- node branch ----
        ln_b16_kernel<<<N_NODES, b256, 0, stream>>>(h, ln_n1_g + l * 256, ln_n1_b + l * 256, hnb);
        gemm_mfma_kernel<<<dim3(12, 48), b256, 0, stream>>>(hnb, 256, 0, nnWinb + (size_t)l * 196608, 256, 0, nn_bin + l * 768, nullptr, nullptr, 1.0f, qkvb, 768, 1, 256, 0);
        prep_vt_kernel<<<dim3(48, 8), b256, 0, stream>>>(qkvb, 768, 512, VTb);
        attn_mfma_kernel<6><<<dim3(96, 8), b384, 0, stream>>>(qkvb, 768, qkvb + 256, 768, VTb, biasb, attnob);
        gemm_mfma_kernel<<<dim3(4, 48), b256, 0, stream>>>(attnob, 256, 0, nnWoutb + (size_t)l * 65536, 256, 0, nn_bout + l * 256, h, nullptr, 1.0f, h, 256, 0, 256, 0);
        ln_b16_kernel<<<N_NODES, b256, 0, stream>>>(h, ln_n2_g + l * 256, ln_n2_b + l * 256, hnb);
        gemm_mfma_kernel<<<dim3(16, 48), b256, 0, stream>>>(hnb, 256, 0, ffnW1b + (size_t)l * 262144, 256, 0, ffn_b1 + l * 1024, nullptr, nullptr, 1.0f, midb, 1024, 1, 256, 1);
        gemm_mfma_kernel<<<dim3(4, 48), b256, 0, stream>>>(midb, 1024, 0, ffnW2b + (size_t)l * 262144, 1024, 0, ffn_b2 + l * 256, h, nullptr, 1.0f, h, 256, 0, 1024, 0);
    }

    ln_out_kernel<<<S_SINK, b256, 0, stream>>>(sinkq, ln_og, ln_ob, (float*)d_out);
}

// Round 6
// 724.247 us; speedup vs baseline: 11.4772x; 1.0415x over previous
//
#include <hip/hip_runtime.h>
#include <hip/hip_bf16.h>

#define N_NODES 3072
#define S_SINK  256
#define DIN     64

typedef __attribute__((ext_vector_type(8))) short short8v;
typedef __attribute__((ext_vector_type(4))) float f32x4;

#define LOG2E 1.4426950408889634f

#if defined(__has_builtin)
#if __has_builtin(__builtin_amdgcn_exp2f)
#define EXP2(x) __builtin_amdgcn_exp2f(x)
#else
#define EXP2(x) exp2f(x)
#endif
#else
#define EXP2(x) exp2f(x)
#endif

static __device__ __forceinline__ float gelu_exact(float v) {
    return 0.5f * v * (1.0f + erff(v * 0.70710678118654752f));
}
static __device__ __forceinline__ unsigned short f2b_rne(float f) {
    unsigned int b = __float_as_uint(f);
    b += 0x7fffu + ((b >> 16) & 1u);
    return (unsigned short)(b >> 16);
}
// f32 -> fp8 e5m2 (RNE, clamp, flush-to-zero on underflow)
static __device__ __forceinline__ unsigned char f2e5m2(float f) {
    unsigned u = __float_as_uint(f);
    unsigned s = (u >> 24) & 0x80u;
    int e = (int)((u >> 23) & 0xffu);
    unsigned m = u & 0x7fffffu;
    m += 0x0fffffu + ((m >> 21) & 1u);
    if (m >> 23) { m = 0; e += 1; }
    int ee = e - 112;
    if (ee <= 0) return (unsigned char)s;
    if (ee >= 31) return (unsigned char)(s | 0x7bu);
    return (unsigned char)(s | ((unsigned)ee << 2) | (m >> 21));
}
// fp8 e5m2 byte -> f32 (via bf16 bit pattern); byte==0 decodes to 2^-15 (negligible here)
static __device__ __forceinline__ float e5m2f(unsigned b) {
    unsigned bf = ((b & 0x80u) << 8) | (((b & 0x7fu) << 5) + (112u << 7));
    return __uint_as_float(bf << 16);
}

// ---------------- one-launch f32 -> bf16 weight conversion ----------------
struct CvtJobs {
    const float* src[9];
    unsigned short* dst[9];
    int cnt4[9];           // element count / 4 per segment
};
__global__ __launch_bounds__(256) void cvt_all_kernel(CvtJobs j, int total4) {
    int i = blockIdx.x * 256 + threadIdx.x;
    if (i >= total4) return;
    int s = 0, base = 0;
    while (s < 9 && i >= base + j.cnt4[s]) { base += j.cnt4[s]; ++s; }
    int off = (i - base) * 4;
    float4 v = *(const float4*)(j.src[s] + off);
    uint2 o;
    o.x = (unsigned)f2b_rne(v.x) | ((unsigned)f2b_rne(v.y) << 16);
    o.y = (unsigned)f2b_rne(v.z) | ((unsigned)f2b_rne(v.w) << 16);
    *(uint2*)(j.dst[s] + off) = o;
}

// ---------------- node encode: h = x@Wp.T + b + pe (writes f32 h and bf16 hb) ----------------
__global__ __launch_bounds__(256) void node_encode_kernel(
    const float* __restrict__ x, const float* __restrict__ C,
    const unsigned char* __restrict__ mask,
    const float* __restrict__ Wp, const float* __restrict__ bp,
    const float* __restrict__ peW, const float* __restrict__ peb,
    const float* __restrict__ peg, const float* __restrict__ pebt,
    const float* __restrict__ gate,
    float* __restrict__ h, unsigned short* __restrict__ hb)
{
    int i = blockIdx.x, t = threadIdx.x;
    __shared__ float xs[DIN];
    __shared__ float r1[256], r2[256];
    __shared__ float zs[20];
    if (t < DIN) xs[t] = x[i * DIN + t];
    float c  = C[i * 256 + t];
    float cc = fminf(fmaxf(c, 0.0f), 1.0f);
    r1[t] = cc; r2[t] = cc * cc;
    __syncthreads();
    for (int s = 128; s > 0; s >>= 1) { if (t < s) { r1[t] += r1[t + s]; r2[t] += r2[t + s]; } __syncthreads(); }
    float cm  = r1[0] * (1.0f / 256.0f);
    float cms = r2[0] * (1.0f / 256.0f);
    __syncthreads();
    r1[t] = cc; r2[t] = cc;
    __syncthreads();
    for (int s = 128; s > 0; s >>= 1) { if (t < s) { r1[t] = fmaxf(r1[t], r1[t + s]); r2[t] = fminf(r2[t], r2[t + s]); } __syncthreads(); }
    float cmax = r1[0], cmin = r2[0];
    __syncthreads();
    if (t == 0) {
        float var  = fmaxf(cms - cm * cm, 0.0f);
        float cstd = sqrtf(var);
        zs[0] = cm; zs[1] = cmax; zs[2] = cmin; zs[3] = cstd;
        float w = 0.15f + 1e-6f;
        for (int k = 0; k < 8; ++k) {
            float ck = (float)k / 7.0f;
            float d1 = (cm   - ck) / w;
            float d2 = (cmax - ck) / w;
            zs[4 + k]  = expf(-0.5f * d1 * d1);
            zs[12 + k] = expf(-0.5f * d2 * d2);
        }
    }
    __syncthreads();
    float pl = peb[t];
    #pragma unroll
    for (int f = 0; f < 20; ++f) pl += zs[f] * peW[t * 20 + f];
    r1[t] = pl; r2[t] = pl * pl;
    __syncthreads();
    for (int s = 128; s > 0; s >>= 1) { if (t < s) { r1[t] += r1[t + s]; r2[t] += r2[t + s]; } __syncthreads(); }
    float m  = r1[0] * (1.0f / 256.0f);
    float vv = fmaxf(r2[0] * (1.0f / 256.0f) - m * m, 0.0f);
    float pe = (pl - m) * rsqrtf(vv + 1e-5f) * peg[t] + pebt[t];
    pe *= gate[0];
    if (mask[i] != 0) pe = 0.0f;
    float hv = bp[t];
    #pragma unroll
    for (int k = 0; k < DIN; ++k) hv += xs[k] * Wp[t * DIN + k];
    float o = hv + pe;
    h[(size_t)i * 256 + t] = o;
    hb[(size_t)i * 256 + t] = f2b_rne(o);
}

// ---------------- Cnb = bf16(C / (||C||+1e-6)) ----------------
__global__ __launch_bounds__(256) void cn_kernel(const float* __restrict__ C, unsigned short* __restrict__ Cnb) {
    int i = blockIdx.x, t = threadIdx.x;
    __shared__ float r1[256];
    float v = C[(size_t)i * 256 + t];
    r1[t] = v * v;
    __syncthreads();
    for (int s = 128; s > 0; s >>= 1) { if (t < s) r1[t] += r1[t + s]; __syncthreads(); }
    float nrm = sqrtf(r1[0]) + 1e-6f;
    Cnb[(size_t)i * 256 + t] = f2b_rne(v / nrm);
}

// ---------------- maskadd[j] = -10000 * log2e * mask[j] (log2 domain) ----------------
__global__ __launch_bounds__(256) void maskadd_kernel(const unsigned char* __restrict__ mask, float* __restrict__ ma) {
    int j = blockIdx.x * 256 + threadIdx.x;
    if (j < N_NODES) ma[j] = -10000.0f * LOG2E * (float)mask[j];
}

// ---------------- CTb[s][j] = bf16(log2e*beta*C[j][s] + maskadd[j]) ----------------
__global__ __launch_bounds__(256) void transpose_b16_kernel(const float* __restrict__ C, const float* __restrict__ beta,
                                                            const float* __restrict__ maskadd, unsigned short* __restrict__ CTb) {
    __shared__ float tile[32][33];
    int bx = blockIdx.x * 32;
    int by = blockIdx.y * 32;
    int tx = threadIdx.x & 31, ty = threadIdx.x >> 5;
    float bt = beta[0] * LOG2E;
    #pragma unroll
    for (int r = 0; r < 4; ++r) {
        int row = bx + ty + r * 8;
        tile[ty + r * 8][tx] = C[(size_t)row * 256 + by + tx];
    }
    __syncthreads();
    #pragma unroll
    for (int r = 0; r < 4; ++r) {
        int srow = by + ty + r * 8;
        CTb[(size_t)srow * 3072 + bx + tx] = f2b_rne(bt * tile[tx][ty + r * 8] + maskadd[bx + tx]);
    }
}

// ---------------- gather rows -> bf16 ----------------
__global__ __launch_bounds__(256) void gather_b16_kernel(const float* __restrict__ h, const int* __restrict__ idx,
                                                         unsigned short* __restrict__ sg) {
    int s = blockIdx.x, t = threadIdx.x;
    sg[(size_t)s * 256 + t] = f2b_rne(h[(size_t)idx[s] * 256 + t]);
}

// ---------------- LayerNorm over 256 channels -> bf16 ----------------
__global__ __launch_bounds__(256) void ln_b16_kernel(const float* __restrict__ in, const float* __restrict__ g,
                                                     const float* __restrict__ b, unsigned short* __restrict__ out) {
    int i = blockIdx.x, t = threadIdx.x;
    __shared__ float r1[256], r2[256];
    float v = in[(size_t)i * 256 + t];
    r1[t] = v; r2[t] = v * v;
    __syncthreads();
    for (int s = 128; s > 0; s >>= 1) { if (t < s) { r1[t] += r1[t + s]; r2[t] += r2[t + s]; } __syncthreads(); }
    float m  = r1[0] * (1.0f / 256.0f);
    float vv = fmaxf(r2[0] * (1.0f / 256.0f) - m * m, 0.0f);
    out[(size_t)i * 256 + t] = f2b_rne((v - m) * rsqrtf(vv + 1e-5f) * g[t] + b[t]);
}

// final LN -> d_out as float32
__global__ __launch_bounds__(256) void ln_out_kernel(const float* __restrict__ in, const float* __restrict__ g,
                                                     const float* __restrict__ b, float* __restrict__ out) {
    int i = blockIdx.x, t = threadIdx.x;
    __shared__ float r1[256], r2[256];
    float v = in[(size_t)i * 256 + t];
    r1[t] = v; r2[t] = v * v;
    __syncthreads();
    for (int s = 128; s > 0; s >>= 1) { if (t < s) { r1[t] += r1[t + s]; r2[t] += r2[t + s]; } __syncthreads(); }
    float m  = r1[0] * (1.0f / 256.0f);
    float vv = fmaxf(r2[0] * (1.0f / 256.0f) - m * m, 0.0f);
    out[(size_t)i * 256 + t] = (v - m) * rsqrtf(vv + 1e-5f) * g[t] + b[t];
}

// ---------------- MFMA GEMM: out = epi((scale*scmul)*(A@W^T) + bias) [+res] ----------------
// A,W bf16 row-major. omode: 0=f32 (+optional bf16 mirror out2), 1=bf16, 2=fp8 e5m2.
__global__ __launch_bounds__(256) void gemm_mfma_kernel(
    const unsigned short* __restrict__ A_, int lda,
    const unsigned short* __restrict__ W_, int ldw,
    const float* __restrict__ bias,
    const float* __restrict__ res,
    const float* __restrict__ scale, float scmul,
    void* __restrict__ out_, void* __restrict__ out2_, int ldo, int omode,
    int K, int act)
{
    __shared__ unsigned short As[64][72];
    __shared__ unsigned short Ws[64][72];
    int tid = threadIdx.x;
    int lane = tid & 63, wid = tid >> 6;
    int c15 = lane & 15, g = lane >> 4;
    int wm = wid & 1, wn = wid >> 1;
    int row0 = blockIdx.y * 64, col0 = blockIdx.x * 64;
    f32x4 acc[2][2];
    const f32x4 zf = {0.f, 0.f, 0.f, 0.f};
    acc[0][0] = zf; acc[0][1] = zf; acc[1][0] = zf; acc[1][1] = zf;

    for (int k0 = 0; k0 < K; k0 += 64) {
        #pragma unroll
        for (int hh = 0; hh < 2; ++hh) {
            int cid = tid + hh * 256;
            int rr = cid >> 3, cc = (cid & 7) * 8;
            short8v va = *(const short8v*)(A_ + (size_t)(row0 + rr) * lda + k0 + cc);
            short8v vw = *(const short8v*)(W_ + (size_t)(col0 + rr) * ldw + k0 + cc);
            *(short8v*)(&As[rr][cc]) = va;
            *(short8v*)(&Ws[rr][cc]) = vw;
        }
        __syncthreads();
        #pragma unroll
        for (int ks = 0; ks < 2; ++ks) {
            short8v a0 = *(const short8v*)(&As[wm * 32 + c15][ks * 32 + g * 8]);
            short8v a1 = *(const short8v*)(&As[wm * 32 + 16 + c15][ks * 32 + g * 8]);
            short8v w0 = *(const short8v*)(&Ws[wn * 32 + c15][ks * 32 + g * 8]);
            short8v w1 = *(const short8v*)(&Ws[wn * 32 + 16 + c15][ks * 32 + g * 8]);
            acc[0][0] = __builtin_amdgcn_mfma_f32_16x16x32_bf16(a0, w0, acc[0][0], 0, 0, 0);
            acc[0][1] = __builtin_amdgcn_mfma_f32_16x16x32_bf16(a0, w1, acc[0][1], 0, 0, 0);
            acc[1][0] = __builtin_amdgcn_mfma_f32_16x16x32_bf16(a1, w0, acc[1][0], 0, 0, 0);
            acc[1][1] = __builtin_amdgcn_mfma_f32_16x16x32_bf16(a1, w1, acc[1][1], 0, 0, 0);
        }
        __syncthreads();
    }
    float sc = (scale ? *scale : 1.0f) * scmul;
    #pragma unroll
    for (int nf = 0; nf < 2; ++nf) {
        int n = col0 + wn * 32 + nf * 16 + c15;
        float bv = bias ? bias[n] : 0.0f;
        #pragma unroll
        for (int mf = 0; mf < 2; ++mf) {
            #pragma unroll
            for (int r = 0; r < 4; ++r) {
                int m = row0 + wm * 32 + mf * 16 + g * 4 + r;
                float v = acc[mf][nf][r] * sc + bv;
                if (act) v = gelu_exact(v);
                if (res) v += res[(size_t)m * ldo + n];
                if (omode == 0) {
                    ((float*)out_)[(size_t)m * ldo + n] = v;
                    if (out2_) ((unsigned short*)out2_)[(size_t)m * ldo + n] = f2b_rne(v);
                } else if (omode == 1) {
                    ((unsigned short*)out_)[(size_t)m * ldo + n] = f2b_rne(v);
                } else {
                    ((unsigned char*)out_)[(size_t)m * ldo + n] = f2e5m2(v);
                }
            }
        }
    }
}

// ---------------- prep: V slice (bf16 src) -> VT_bf16[h][32][3072] ----------------
__global__ __launch_bounds__(256) void prep_vt_kernel(const unsigned short* __restrict__ src, int ld, int voff,
                                                      unsigned short* __restrict__ VTb)
{
    int h = blockIdx.y, k0 = blockIdx.x * 64, t = threadIdx.x;
    __shared__ unsigned short tl[64][33];
    #pragma unroll
    for (int it = 0; it < 8; ++it) {
        int idx = t + 256 * it;
        int j = idx >> 5, d = idx & 31;
        tl[j][d] = src[(size_t)(k0 + j) * ld + voff + h * 32 + d];
    }
    __syncthreads();
    #pragma unroll
    for (int it = 0; it < 8; ++it) {
        int idx = t + 256 * it;
        int d = idx >> 6, j = idx & 63;
        VTb[((size_t)h * 32 + d) * 3072 + k0 + j] = tl[j][d];
    }
}

// ---------------- split-K MFMA flash attention, log2 domain ----------------
// BF8: node bias is fp8 e5m2; else bf16. Low-VGPR r4-style loop.
template<int SPLIT, int BF8>
__global__ __launch_bounds__(64 * SPLIT) void attn_mfma_kernel(
    const unsigned short* __restrict__ Qb, int ldq,
    const unsigned short* __restrict__ Ksrc, int ldk,
    const unsigned short* __restrict__ VTb,
    const void* __restrict__ biasp,
    unsigned short* __restrict__ out)
{
    constexpr int KT = 48 / SPLIT;
    __shared__ unsigned short P_all[SPLIT * 32 * 72];
    __shared__ float ml[SPLIT * 64];
    const int head = blockIdx.y;
    const int i0 = blockIdx.x * 32;
    const int tid = threadIdx.x;
    const int lane = tid & 63, w = tid >> 6;
    const int c15 = lane & 15, g = lane >> 4;
    unsigned short* P_lds = P_all + w * (32 * 72);
    const unsigned short* Kh  = Ksrc + (size_t)head * 32;
    const unsigned short* VTh = VTb + (size_t)head * 32 * 3072;
    const f32x4 zf = {0.f, 0.f, 0.f, 0.f};
    const float rsl2 = 0.25503164113124427f;   // log2(e)/sqrt(32)

    short8v qf[2];
    #pragma unroll
    for (int nf = 0; nf < 2; ++nf)
        qf[nf] = *(const short8v*)(Qb + (size_t)(i0 + nf * 16 + c15) * ldq + head * 32 + g * 8);

    float m_[2] = {-1e30f, -1e30f};
    float l_[2] = {0.f, 0.f};
    f32x4 acc[2][2];
    acc[0][0] = zf; acc[0][1] = zf; acc[1][0] = zf; acc[1][1] = zf;

    for (int kt = 0; kt < KT; ++kt) {
        const int k0 = (w * KT + kt) * 64;
        short8v kf[4];
        #pragma unroll
        for (int mf = 0; mf < 4; ++mf)
            kf[mf] = *(const short8v*)(Kh + (size_t)(k0 + mf * 16 + c15) * ldk + g * 8);
        f32x4 s[4][2];
        __builtin_amdgcn_s_setprio(1);
        #pragma unroll
        for (int mf = 0; mf < 4; ++mf)
            #pragma unroll
            for (int nf = 0; nf < 2; ++nf)
                s[mf][nf] = __builtin_amdgcn_mfma_f32_16x16x32_bf16(kf[mf], qf[nf], zf, 0, 0, 0);
        __builtin_amdgcn_s_setprio(0);
        // scale + bias (log2 domain)
        #pragma unroll
        for (int nf = 0; nf < 2; ++nf) {
            const int q = i0 + nf * 16 + c15;
            if (BF8) {
                const unsigned char* bp = (const unsigned char*)biasp + (size_t)q * 3072 + k0;
                #pragma unroll
                for (int mf = 0; mf < 4; ++mf) {
                    unsigned bv = *(const unsigned*)(bp + mf * 16 + g * 4);
                    s[mf][nf][0] = s[mf][nf][0] * rsl2 + e5m2f(bv & 0xffu);
                    s[mf][nf][1] = s[mf][nf][1] * rsl2 + e5m2f((bv >> 8) & 0xffu);
                    s[mf][nf][2] = s[mf][nf][2] * rsl2 + e5m2f((bv >> 16) & 0xffu);
                    s[mf][nf][3] = s[mf][nf][3] * rsl2 + e5m2f(bv >> 24);
                }
            } else {
                const unsigned short* bp = (const unsigned short*)biasp + (size_t)q * 3072 + k0;
                #pragma unroll
                for (int mf = 0; mf < 4; ++mf) {
                    uint2 bv = *(const uint2*)(bp + mf * 16 + g * 4);
                    s[mf][nf][0] = s[mf][nf][0] * rsl2 + __uint_as_float(bv.x << 16);
                    s[mf][nf][1] = s[mf][nf][1] * rsl2 + __uint_as_float(bv.x & 0xffff0000u);
                    s[mf][nf][2] = s[mf][nf][2] * rsl2 + __uint_as_float(bv.y << 16);
                    s[mf][nf][3] = s[mf][nf][3] * rsl2 + __uint_as_float(bv.y & 0xffff0000u);
                }
            }
        }
        // online softmax (defer-max, T13)
        #pragma unroll
        for (int nf = 0; nf < 2; ++nf) {
            float t01 = fmaxf(fmaxf(s[0][nf][0], s[0][nf][1]), fmaxf(s[0][nf][2], s[0][nf][3]));
            float t23 = fmaxf(fmaxf(s[1][nf][0], s[1][nf][1]), fmaxf(s[1][nf][2], s[1][nf][3]));
            float t45 = fmaxf(fmaxf(s[2][nf][0], s[2][nf][1]), fmaxf(s[2][nf][2], s[2][nf][3]));
            float t67 = fmaxf(fmaxf(s[3][nf][0], s[3][nf][1]), fmaxf(s[3][nf][2], s[3][nf][3]));
            float tmax = fmaxf(fmaxf(t01, t23), fmaxf(t45, t67));
            tmax = fmaxf(tmax, __shfl_xor(tmax, 16));
            tmax = fmaxf(tmax, __shfl_xor(tmax, 32));
            if (!__all(tmax <= m_[nf] + 8.0f)) {
                float mn = fmaxf(m_[nf], tmax);
                float scl = EXP2(m_[nf] - mn);
                m_[nf] = mn;
                l_[nf] *= scl;
                #pragma unroll
                for (int mf = 0; mf < 2; ++mf) {
                    acc[mf][nf][0] *= scl; acc[mf][nf][1] *= scl;
                    acc[mf][nf][2] *= scl; acc[mf][nf][3] *= scl;
                }
            }
            float mcur = m_[nf];
            float ts = 0.f;
            #pragma unroll
            for (int mf = 0; mf < 4; ++mf)
                #pragma unroll
                for (int r = 0; r < 4; ++r) {
                    float p = EXP2(s[mf][nf][r] - mcur);
                    s[mf][nf][r] = p;
                    ts += p;
                }
            ts += __shfl_xor(ts, 16);
            ts += __shfl_xor(ts, 32);
            l_[nf] += ts;
            const int q = nf * 16 + c15;
            #pragma unroll
            for (int mf = 0; mf < 4; ++mf) {
                uint2 pv;
                pv.x = (unsigned)f2b_rne(s[mf][nf][0]) | ((unsigned)f2b_rne(s[mf][nf][1]) << 16);
                pv.y = (unsigned)f2b_rne(s[mf][nf][2]) | ((unsigned)f2b_rne(s[mf][nf][3]) << 16);
                *(uint2*)(P_lds + q * 72 + mf * 16 + g * 4) = pv;
            }
        }
        // O^T += V^T . P^T
        #pragma unroll
        for (int ks = 0; ks < 2; ++ks) {
            short8v pB[2], vA[2];
            #pragma unroll
            for (int nf = 0; nf < 2; ++nf)
                pB[nf] = *(const short8v*)(P_lds + (nf * 16 + c15) * 72 + ks * 32 + g * 8);
            #pragma unroll
            for (int mf = 0; mf < 2; ++mf)
                vA[mf] = *(const short8v*)(VTh + (size_t)(mf * 16 + c15) * 3072 + k0 + ks * 32 + g * 8);
            __builtin_amdgcn_s_setprio(1);
            #pragma unroll
            for (int mf = 0; mf < 2; ++mf)
                #pragma unroll
                for (int nf = 0; nf < 2; ++nf)
                    acc[mf][nf] = __builtin_amdgcn_mfma_f32_16x16x32_bf16(vA[mf], pB[nf], acc[mf][nf], 0, 0, 0);
            __builtin_amdgcn_s_setprio(0);
        }
    }

    // partials -> LDS, cross-split combine
    float* Olds = (float*)P_all;
    #pragma unroll
    for (int nf = 0; nf < 2; ++nf) {
        int q = nf * 16 + c15;
        #pragma unroll
        for (int mf = 0; mf < 2; ++mf)
            *(f32x4*)(Olds + w * 1152 + q * 36 + mf * 16 + g * 4) = acc[mf][nf];
        if (g == 0) {
            ml[w * 64 + q] = m_[nf];
            ml[w * 64 + 32 + q] = l_[nf];
        }
    }
    __syncthreads();
    if (tid < 256) {
        int q = tid >> 3, d0 = (tid & 7) * 4;
        float M = -1e30f;
        #pragma unroll
        for (int s = 0; s < SPLIT; ++s) M = fmaxf(M, ml[s * 64 + q]);
        float wsv[SPLIT];
        float L = 0.f;
        #pragma unroll
        for (int s = 0; s < SPLIT; ++s) {
            float wv = EXP2(ml[s * 64 + q] - M);
            wsv[s] = wv;
            L += wv * ml[s * 64 + 32 + q];
        }
        float invL = 1.0f / L;
        float v0 = 0, v1 = 0, v2 = 0, v3 = 0;
        #pragma unroll
        for (int s = 0; s < SPLIT; ++s) {
            const float* op = Olds + s * 1152 + q * 36 + d0;
            v0 += wsv[s] * op[0]; v1 += wsv[s] * op[1];
            v2 += wsv[s] * op[2]; v3 += wsv[s] * op[3];
        }
        uint2 pk;
        pk.x = (unsigned)f2b_rne(v0 * invL) | ((unsigned)f2b_rne(v1 * invL) << 16);
        pk.y = (unsigned)f2b_rne(v2 * invL) | ((unsigned)f2b_rne(v3 * invL) << 16);
        *(uint2*)(out + (size_t)(i0 + q) * 256 + head * 32 + d0) = pk;
    }
}

extern "C" void kernel_launch(void* const* d_in, const int* in_sizes, int n_in,
                              void* d_out, int out_size, void* d_ws, size_t ws_size,
                              hipStream_t stream)
{
    const float* x        = (const float*)d_in[0];
    const float* C        = (const float*)d_in[1];
    const int*   sidx     = (const int*)d_in[2];
    const unsigned char* mask = (const unsigned char*)d_in[3];
    const float* proj_W   = (const float*)d_in[4];
    const float* proj_b   = (const float*)d_in[5];
    const float* peW      = (const float*)d_in[6];
    const float* peb      = (const float*)d_in[7];
    const float* peg      = (const float*)d_in[8];
    const float* pebt     = (const float*)d_in[9];
    const float* pe_gate  = (const float*)d_in[10];
    const float* alpha_nn = (const float*)d_in[11];
    const float* beta_sn  = (const float*)d_in[12];
    const float* sqW      = (const float*)d_in[13];
    const float* sqb      = (const float*)d_in[14];
    const float* sn_Win   = (const float*)d_in[15];
    const float* sn_bin   = (const float*)d_in[16];
    const float* sn_Wout  = (const float*)d_in[17];
    const float* sn_bout  = (const float*)d_in[18];
    const float* nn_Win   = (const float*)d_in[19];
    const float* nn_bin   = (const float*)d_in[20];
    const float* nn_Wout  = (const float*)d_in[21];
    const float* nn_bout  = (const float*)d_in[22];
    const float* ln_s_g   = (const float*)d_in[23];
    const float* ln_s_b   = (const float*)d_in[24];
    const float* ln_n1_g  = (const float*)d_in[25];
    const float* ln_n1_b  = (const float*)d_in[26];
    const float* ln_n2_g  = (const float*)d_in[27];
    const float* ln_n2_b  = (const float*)d_in[28];
    const float* ffn_W1   = (const float*)d_in[29];
    const float* ffn_b1   = (const float*)d_in[30];
    const float* ffn_W2   = (const float*)d_in[31];
    const float* ffn_b2   = (const float*)d_in[32];
    const float* ffs_W1   = (const float*)d_in[33];
    const float* ffs_b1   = (const float*)d_in[34];
    const float* ffs_W2   = (const float*)d_in[35];
    const float* ffs_b2   = (const float*)d_in[36];
    const float* ln_og    = (const float*)d_in[37];
    const float* ln_ob    = (const float*)d_in[38];

    float* ws = (float*)d_ws;
    float* h       = ws;                                          // 786432 f
    float* sinkq   = ws + 786432;                                 // 65536
    float* maskadd = ws + 851968;                                 // 4096
    unsigned short* Cnb    = (unsigned short*)(ws + 856064);      // 393216 f
    unsigned short* hb     = (unsigned short*)(ws + 1249280);     // 393216 f
    unsigned short* hnb    = (unsigned short*)(ws + 1642496);     // 393216 f
    unsigned short* attnob = (unsigned short*)(ws + 2035712);     // 393216 f
    unsigned short* sqnb   = (unsigned short*)(ws + 2428928);     // 32768 f
    unsigned short* sgb    = (unsigned short*)(ws + 2461696);     // 32768 f
    unsigned short* sinkqb = (unsigned short*)(ws + 2494464);     // 32768 f
    unsigned short* VTb    = (unsigned short*)(ws + 2527232);     // 393216 f
    unsigned short* CTb    = (unsigned short*)(ws + 2920448);     // 393216 f
    unsigned char*  biasb8 = (unsigned char*)(ws + 3313664);      // 2359296 f (3072x3072 fp8)
    unsigned short* wb     = (unsigned short*)(ws + 5672960);     // 2392064 f
    float* big     = ws + 8065024;                                // 1572864 f union
    unsigned short* sqWb    = wb;
    unsigned short* snWinb  = wb + 65536;
    unsigned short* snWoutb = wb + 655360;
    unsigned short* nnWinb  = wb + 851968;
    unsigned short* nnWoutb = wb + 1441792;
    unsigned short* ffnW1b  = wb + 1638400;
    unsigned short* ffnW2b  = wb + 2424832;
    unsigned short* ffsW1b  = wb + 3211264;
    unsigned short* ffsW2b  = wb + 3997696;
    unsigned short* q_sb  = (unsigned short*)big;                 // 256x256
    unsigned short* kv_sb = (unsigned short*)(big + 32768);       // 3072x512
    unsigned short* mid_sb= (unsigned short*)(big + 819200);      // 256x1024
    unsigned short* qkvb  = (unsigned short*)big;                 // 3072x768
    unsigned short* midb  = (unsigned short*)big;                 // 3072x1024

    dim3 b256(256), b384(384);

    CvtJobs cj;
    cj.src[0] = sqW;     cj.dst[0] = sqWb;    cj.cnt4[0] = 16384;
    cj.src[1] = sn_Win;  cj.dst[1] = snWinb;  cj.cnt4[1] = 147456;
    cj.src[2] = sn_Wout; cj.dst[2] = snWoutb; cj.cnt4[2] = 49152;
    cj.src[3] = nn_Win;  cj.dst[3] = nnWinb;  cj.cnt4[3] = 147456;
    cj.src[4] = nn_Wout; cj.dst[4] = nnWoutb; cj.cnt4[4] = 49152;
    cj.src[5] = ffn_W1;  cj.dst[5] = ffnW1b;  cj.cnt4[5] = 196608;
    cj.src[6] = ffn_W2;  cj.dst[6] = ffnW2b;  cj.cnt4[6] = 196608;
    cj.src[7] = ffs_W1;  cj.dst[7] = ffsW1b;  cj.cnt4[7] = 196608;
    cj.src[8] = ffs_W2;  cj.dst[8] = ffsW2b;  cj.cnt4[8] = 196608;
    cvt_all_kernel<<<4672, b256, 0, stream>>>(cj, 1196032);

    maskadd_kernel<<<12, b256, 0, stream>>>(mask, maskadd);
    node_encode_kernel<<<N_NODES, b256, 0, stream>>>(x, C, mask, proj_W, proj_b, peW, peb, peg, pebt, pe_gate, h, hb);
    gather_b16_kernel<<<S_SINK, b256, 0, stream>>>(h, sidx, sgb);
    gemm_mfma_kernel<<<dim3(4, 4), b256, 0, stream>>>(sgb, 256, sqWb, 256, sqb, nullptr, nullptr, 1.0f, sinkq, nullptr, 256, 0, 256, 0);
    cn_kernel<<<N_NODES, b256, 0, stream>>>(C, Cnb);
    transpose_b16_kernel<<<dim3(96, 8), b256, 0, stream>>>(C, beta_sn, maskadd, CTb);
    gemm_mfma_kernel<<<dim3(48, 48), b256, 0, stream>>>(Cnb, 256, Cnb, 256, maskadd, nullptr, alpha_nn, LOG2E, biasb8, nullptr, 3072, 2, 256, 0);

    for (int l = 0; l < 3; ++l) {
        // ---- sink branch ----
        ln_b16_kernel<<<S_SINK, b256, 0, stream>>>(sinkq, ln_s_g + l * 256, ln_s_b + l * 256, sqnb);
        gemm_mfma_kernel<<<dim3(4, 4), b256, 0, stream>>>(sqnb, 256, snWinb + (size_t)l * 196608, 256, sn_bin + l * 768, nullptr, nullptr, 1.0f, q_sb, nullptr, 256, 1, 256, 0);
        gemm_mfma_kernel<<<dim3(8, 48), b256, 0, stream>>>(hb, 256, snWinb + (size_t)l * 196608 + 65536, 256, sn_bin + l * 768 + 256, nullptr, nullptr, 1.0f, kv_sb, nullptr, 512, 1, 256, 0);
        prep_vt_kernel<<<dim3(48, 8), b256, 0, stream>>>(kv_sb, 512, 256, VTb);
        attn_mfma_kernel<6, 0><<<dim3(8, 8), b384, 0, stream>>>(q_sb, 256, kv_sb, 512, VTb, CTb, attnob);
        gemm_mfma_kernel<<<dim3(4, 4), b256, 0, stream>>>(attnob, 256, snWoutb + (size_t)l * 65536, 256, sn_bout + l * 256, sinkq, nullptr, 1.0f, sinkq, sinkqb, 256, 0, 256, 0);
        gemm_mfma_kernel<<<dim3(16, 4), b256, 0, stream>>>(sinkqb, 256, ffsW1b + (size_t)l * 262144, 256, ffs_b1 + l * 1024, nullptr, nullptr, 1.0f, mid_sb, nullptr, 1024, 1, 256, 1);
        gemm_mfma_kernel<<<dim3(4, 4), b256, 0, stream>>>(mid_sb, 1024, ffsW2b + (size_t)l * 262144, 1024, ffs_b2 + l * 256, sinkq, nullptr, 1.0f, sinkq, nullptr, 256, 0, 1024, 0);

        // ---- node branch ----
        ln_b16_kernel<<<N_NODES, b256, 0, stream>>>(h, ln_n1_g + l * 256, ln_n1_b + l * 256, hnb);
        gemm_mfma_kernel<<<dim3(12, 48), b256, 0, stream>>>(hnb, 256, nnWinb + (size_t)l * 196608, 256, nn_bin + l * 768, nullptr, nullptr, 1.0f, qkvb, nullptr, 768, 1, 256, 0);
        prep_vt_kernel<<<dim3(48, 8), b256, 0, stream>>>(qkvb, 768, 512, VTb);
        attn_mfma_kernel<6, 1><<<dim3(96, 8), b384, 0, stream>>>(qkvb, 768, qkvb + 256, 768, VTb, biasb8, attnob);
        gemm_mfma_kernel<<<dim3(4, 48), b256, 0, stream>>>(attnob, 256, nnWoutb + (size_t)l * 65536, 256, nn_bout + l * 256, h, nullptr, 1.0f, h, nullptr, 256, 0, 256, 0);
        ln_b16_kernel<<<N_NODES, b256, 0, stream>>>(h, ln_n2_g + l * 256, ln_n2_b + l * 256, hnb);
        gemm_mfma_kernel<<<dim3(16, 48), b256, 0, stream>>>(hnb, 256, ffnW1b + (size_t)l * 262144, 256, ffn_b1 + l * 1024, nullptr, nullptr, 1.0f, midb, nullptr, 1024, 1, 256, 1);
        gemm_mfma_kernel<<<dim3(4, 48), b256, 0, stream>>>(midb, 1024, ffnW2b + (size_t)l * 262144, 1024, ffn_b2 + l * 256, h, nullptr, 1.0f, h, hb, 256, 0, 1024, 0);
    }

    ln_out_kernel<<<S_SINK, b256, 0, stream>>>(sinkq, ln_og, ln_ob, (float*)d_out);
}

// Round 8
// 698.458 us; speedup vs baseline: 11.9010x; 1.0369x over previous
//
#include <hip/hip_runtime.h>
#include <hip/hip_bf16.h>

#define N_NODES 3072
#define S_SINK  256
#define DIN     64

typedef __attribute__((ext_vector_type(8))) short short8v;
typedef __attribute__((ext_vector_type(4))) float f32x4;

#define LOG2E 1.4426950408889634f

#if defined(__has_builtin)
#if __has_builtin(__builtin_amdgcn_exp2f)
#define EXP2(x) __builtin_amdgcn_exp2f(x)
#else
#define EXP2(x) exp2f(x)
#endif
#else
#define EXP2(x) exp2f(x)
#endif

static __device__ __forceinline__ float gelu_exact(float v) {
    return 0.5f * v * (1.0f + erff(v * 0.70710678118654752f));
}
static __device__ __forceinline__ unsigned short f2b_rne(float f) {
    unsigned int b = __float_as_uint(f);
    b += 0x7fffu + ((b >> 16) & 1u);
    return (unsigned short)(b >> 16);
}
// pack two f32 -> bf16x2 via v_cvt_pk_bf16_f32 (no builtin on gfx950 — inline asm, T12 recipe)
static __device__ __forceinline__ unsigned pack_b16(float a, float b) {
    unsigned r;
    asm("v_cvt_pk_bf16_f32 %0, %1, %2" : "=v"(r) : "v"(a), "v"(b));
    return r;
}

// ---------------- one-launch f32 -> bf16 weight conversion ----------------
struct CvtJobs {
    const float* src[9];
    unsigned short* dst[9];
    int cnt4[9];
};
__global__ __launch_bounds__(256) void cvt_all_kernel(CvtJobs j, int total4) {
    int i = blockIdx.x * 256 + threadIdx.x;
    if (i >= total4) return;
    int s = 0, base = 0;
    while (s < 9 && i >= base + j.cnt4[s]) { base += j.cnt4[s]; ++s; }
    int off = (i - base) * 4;
    float4 v = *(const float4*)(j.src[s] + off);
    uint2 o;
    o.x = pack_b16(v.x, v.y);
    o.y = pack_b16(v.z, v.w);
    *(uint2*)(j.dst[s] + off) = o;
}

// ---------------- node encode: h = x@Wp.T + b + pe (writes f32 h and bf16 hb) ----------------
__global__ __launch_bounds__(256) void node_encode_kernel(
    const float* __restrict__ x, const float* __restrict__ C,
    const unsigned char* __restrict__ mask,
    const float* __restrict__ Wp, const float* __restrict__ bp,
    const float* __restrict__ peW, const float* __restrict__ peb,
    const float* __restrict__ peg, const float* __restrict__ pebt,
    const float* __restrict__ gate,
    float* __restrict__ h, unsigned short* __restrict__ hb)
{
    int i = blockIdx.x, t = threadIdx.x;
    __shared__ float xs[DIN];
    __shared__ float r1[256], r2[256];
    __shared__ float zs[20];
    if (t < DIN) xs[t] = x[i * DIN + t];
    float c  = C[i * 256 + t];
    float cc = fminf(fmaxf(c, 0.0f), 1.0f);
    r1[t] = cc; r2[t] = cc * cc;
    __syncthreads();
    for (int s = 128; s > 0; s >>= 1) { if (t < s) { r1[t] += r1[t + s]; r2[t] += r2[t + s]; } __syncthreads(); }
    float cm  = r1[0] * (1.0f / 256.0f);
    float cms = r2[0] * (1.0f / 256.0f);
    __syncthreads();
    r1[t] = cc; r2[t] = cc;
    __syncthreads();
    for (int s = 128; s > 0; s >>= 1) { if (t < s) { r1[t] = fmaxf(r1[t], r1[t + s]); r2[t] = fminf(r2[t], r2[t + s]); } __syncthreads(); }
    float cmax = r1[0], cmin = r2[0];
    __syncthreads();
    if (t == 0) {
        float var  = fmaxf(cms - cm * cm, 0.0f);
        float cstd = sqrtf(var);
        zs[0] = cm; zs[1] = cmax; zs[2] = cmin; zs[3] = cstd;
        float w = 0.15f + 1e-6f;
        for (int k = 0; k < 8; ++k) {
            float ck = (float)k / 7.0f;
            float d1 = (cm   - ck) / w;
            float d2 = (cmax - ck) / w;
            zs[4 + k]  = expf(-0.5f * d1 * d1);
            zs[12 + k] = expf(-0.5f * d2 * d2);
        }
    }
    __syncthreads();
    float pl = peb[t];
    #pragma unroll
    for (int f = 0; f < 20; ++f) pl += zs[f] * peW[t * 20 + f];
    r1[t] = pl; r2[t] = pl * pl;
    __syncthreads();
    for (int s = 128; s > 0; s >>= 1) { if (t < s) { r1[t] += r1[t + s]; r2[t] += r2[t + s]; } __syncthreads(); }
    float m  = r1[0] * (1.0f / 256.0f);
    float vv = fmaxf(r2[0] * (1.0f / 256.0f) - m * m, 0.0f);
    float pe = (pl - m) * rsqrtf(vv + 1e-5f) * peg[t] + pebt[t];
    pe *= gate[0];
    if (mask[i] != 0) pe = 0.0f;
    float hv = bp[t];
    #pragma unroll
    for (int k = 0; k < DIN; ++k) hv += xs[k] * Wp[t * DIN + k];
    float o = hv + pe;
    h[(size_t)i * 256 + t] = o;
    hb[(size_t)i * 256 + t] = f2b_rne(o);
}

// ---------------- Cnb = bf16(C / (||C||+1e-6)) ----------------
__global__ __launch_bounds__(256) void cn_kernel(const float* __restrict__ C, unsigned short* __restrict__ Cnb) {
    int i = blockIdx.x, t = threadIdx.x;
    __shared__ float r1[256];
    float v = C[(size_t)i * 256 + t];
    r1[t] = v * v;
    __syncthreads();
    for (int s = 128; s > 0; s >>= 1) { if (t < s) r1[t] += r1[t + s]; __syncthreads(); }
    float nrm = sqrtf(r1[0]) + 1e-6f;
    Cnb[(size_t)i * 256 + t] = f2b_rne(v / nrm);
}

// ---------------- maskadd[j] = -10000 * log2e * mask[j] ----------------
__global__ __launch_bounds__(256) void maskadd_kernel(const unsigned char* __restrict__ mask, float* __restrict__ ma) {
    int j = blockIdx.x * 256 + threadIdx.x;
    if (j < N_NODES) ma[j] = -10000.0f * LOG2E * (float)mask[j];
}

// ---------------- CTb[s][j] = bf16(log2e*beta*C[j][s] + maskadd[j]) ----------------
__global__ __launch_bounds__(256) void transpose_b16_kernel(const float* __restrict__ C, const float* __restrict__ beta,
                                                            const float* __restrict__ maskadd, unsigned short* __restrict__ CTb) {
    __shared__ float tile[32][33];
    int bx = blockIdx.x * 32;
    int by = blockIdx.y * 32;
    int tx = threadIdx.x & 31, ty = threadIdx.x >> 5;
    float bt = beta[0] * LOG2E;
    #pragma unroll
    for (int r = 0; r < 4; ++r) {
        int row = bx + ty + r * 8;
        tile[ty + r * 8][tx] = C[(size_t)row * 256 + by + tx];
    }
    __syncthreads();
    #pragma unroll
    for (int r = 0; r < 4; ++r) {
        int srow = by + ty + r * 8;
        CTb[(size_t)srow * 3072 + bx + tx] = f2b_rne(bt * tile[tx][ty + r * 8] + maskadd[bx + tx]);
    }
}

// ---------------- gather rows -> bf16 ----------------
__global__ __launch_bounds__(256) void gather_b16_kernel(const float* __restrict__ h, const int* __restrict__ idx,
                                                         unsigned short* __restrict__ sg) {
    int s = blockIdx.x, t = threadIdx.x;
    sg[(size_t)s * 256 + t] = f2b_rne(h[(size_t)idx[s] * 256 + t]);
}

// ---------------- LayerNorm over 256 channels -> bf16 ----------------
__global__ __launch_bounds__(256) void ln_b16_kernel(const float* __restrict__ in, const float* __restrict__ g,
                                                     const float* __restrict__ b, unsigned short* __restrict__ out) {
    int i = blockIdx.x, t = threadIdx.x;
    __shared__ float r1[256], r2[256];
    float v = in[(size_t)i * 256 + t];
    r1[t] = v; r2[t] = v * v;
    __syncthreads();
    for (int s = 128; s > 0; s >>= 1) { if (t < s) { r1[t] += r1[t + s]; r2[t] += r2[t + s]; } __syncthreads(); }
    float m  = r1[0] * (1.0f / 256.0f);
    float vv = fmaxf(r2[0] * (1.0f / 256.0f) - m * m, 0.0f);
    out[(size_t)i * 256 + t] = f2b_rne((v - m) * rsqrtf(vv + 1e-5f) * g[t] + b[t]);
}

// final LN -> d_out as float32
__global__ __launch_bounds__(256) void ln_out_kernel(const float* __restrict__ in, const float* __restrict__ g,
                                                     const float* __restrict__ b, float* __restrict__ out) {
    int i = blockIdx.x, t = threadIdx.x;
    __shared__ float r1[256], r2[256];
    float v = in[(size_t)i * 256 + t];
    r1[t] = v; r2[t] = v * v;
    __syncthreads();
    for (int s = 128; s > 0; s >>= 1) { if (t < s) { r1[t] += r1[t + s]; r2[t] += r2[t + s]; } __syncthreads(); }
    float m  = r1[0] * (1.0f / 256.0f);
    float vv = fmaxf(r2[0] * (1.0f / 256.0f) - m * m, 0.0f);
    out[(size_t)i * 256 + t] = (v - m) * rsqrtf(vv + 1e-5f) * g[t] + b[t];
}

// ---------------- MFMA GEMM: out = epi((scale*scmul)*(A@W^T) + bias) [+res] ----------------
// A,W bf16 row-major. omode: 0=f32 (+optional bf16 mirror out2), 1=bf16.
__global__ __launch_bounds__(256) void gemm_mfma_kernel(
    const unsigned short* __restrict__ A_, int lda,
    const unsigned short* __restrict__ W_, int ldw,
    const float* __restrict__ bias,
    const float* __restrict__ res,
    const float* __restrict__ scale, float scmul,
    void* __restrict__ out_, void* __restrict__ out2_, int ldo, int omode,
    int K, int act)
{
    __shared__ unsigned short As[64][72];
    __shared__ unsigned short Ws[64][72];
    int tid = threadIdx.x;
    int lane = tid & 63, wid = tid >> 6;
    int c15 = lane & 15, g = lane >> 4;
    int wm = wid & 1, wn = wid >> 1;
    int row0 = blockIdx.y * 64, col0 = blockIdx.x * 64;
    f32x4 acc[2][2];
    const f32x4 zf = {0.f, 0.f, 0.f, 0.f};
    acc[0][0] = zf; acc[0][1] = zf; acc[1][0] = zf; acc[1][1] = zf;

    for (int k0 = 0; k0 < K; k0 += 64) {
        #pragma unroll
        for (int hh = 0; hh < 2; ++hh) {
            int cid = tid + hh * 256;
            int rr = cid >> 3, cc = (cid & 7) * 8;
            short8v va = *(const short8v*)(A_ + (size_t)(row0 + rr) * lda + k0 + cc);
            short8v vw = *(const short8v*)(W_ + (size_t)(col0 + rr) * ldw + k0 + cc);
            *(short8v*)(&As[rr][cc]) = va;
            *(short8v*)(&Ws[rr][cc]) = vw;
        }
        __syncthreads();
        #pragma unroll
        for (int ks = 0; ks < 2; ++ks) {
            short8v a0 = *(const short8v*)(&As[wm * 32 + c15][ks * 32 + g * 8]);
            short8v a1 = *(const short8v*)(&As[wm * 32 + 16 + c15][ks * 32 + g * 8]);
            short8v w0 = *(const short8v*)(&Ws[wn * 32 + c15][ks * 32 + g * 8]);
            short8v w1 = *(const short8v*)(&Ws[wn * 32 + 16 + c15][ks * 32 + g * 8]);
            acc[0][0] = __builtin_amdgcn_mfma_f32_16x16x32_bf16(a0, w0, acc[0][0], 0, 0, 0);
            acc[0][1] = __builtin_amdgcn_mfma_f32_16x16x32_bf16(a0, w1, acc[0][1], 0, 0, 0);
            acc[1][0] = __builtin_amdgcn_mfma_f32_16x16x32_bf16(a1, w0, acc[1][0], 0, 0, 0);
            acc[1][1] = __builtin_amdgcn_mfma_f32_16x16x32_bf16(a1, w1, acc[1][1], 0, 0, 0);
        }
        __syncthreads();
    }
    float sc = (scale ? *scale : 1.0f) * scmul;
    #pragma unroll
    for (int nf = 0; nf < 2; ++nf) {
        int n = col0 + wn * 32 + nf * 16 + c15;
        float bv = bias ? bias[n] : 0.0f;
        #pragma unroll
        for (int mf = 0; mf < 2; ++mf) {
            #pragma unroll
            for (int r = 0; r < 4; ++r) {
                int m = row0 + wm * 32 + mf * 16 + g * 4 + r;
                float v = acc[mf][nf][r] * sc + bv;
                if (act) v = gelu_exact(v);
                if (res) v += res[(size_t)m * ldo + n];
                if (omode == 0) {
                    ((float*)out_)[(size_t)m * ldo + n] = v;
                    if (out2_) ((unsigned short*)out2_)[(size_t)m * ldo + n] = f2b_rne(v);
                } else {
                    ((unsigned short*)out_)[(size_t)m * ldo + n] = f2b_rne(v);
                }
            }
        }
    }
}

// ---------------- prep: V slice (bf16 src) -> VT_bf16[h][32][3072] ----------------
__global__ __launch_bounds__(256) void prep_vt_kernel(const unsigned short* __restrict__ src, int ld, int voff,
                                                      unsigned short* __restrict__ VTb)
{
    int h = blockIdx.y, k0 = blockIdx.x * 64, t = threadIdx.x;
    __shared__ unsigned short tl[64][33];
    #pragma unroll
    for (int it = 0; it < 8; ++it) {
        int idx = t + 256 * it;
        int j = idx >> 5, d = idx & 31;
        tl[j][d] = src[(size_t)(k0 + j) * ld + voff + h * 32 + d];
    }
    __syncthreads();
    #pragma unroll
    for (int it = 0; it < 8; ++it) {
        int idx = t + 256 * it;
        int d = idx >> 6, j = idx & 63;
        VTb[((size_t)h * 32 + d) * 3072 + k0 + j] = tl[j][d];
    }
}

// ---------------- split-K MFMA flash attention, log2 domain, lean-VALU ----------------
template<int SPLIT>
__global__ __launch_bounds__(64 * SPLIT) void attn_mfma_kernel(
    const unsigned short* __restrict__ Qb, int ldq,
    const unsigned short* __restrict__ Ksrc, int ldk,
    const unsigned short* __restrict__ VTb,
    const unsigned short* __restrict__ biasb,
    unsigned short* __restrict__ out)
{
    constexpr int KT = 48 / SPLIT;
    __shared__ unsigned short P_all[SPLIT * 32 * 72];
    __shared__ float ml[SPLIT * 64];
    const int head = blockIdx.y;
    const int i0 = blockIdx.x * 32;
    const int tid = threadIdx.x;
    const int lane = tid & 63, w = tid >> 6;
    const int c15 = lane & 15, g = lane >> 4;
    unsigned short* P_lds = P_all + w * (32 * 72);
    const unsigned short* Kh  = Ksrc + (size_t)head * 32;
    const unsigned short* VTh = VTb + (size_t)head * 32 * 3072;
    const f32x4 zf = {0.f, 0.f, 0.f, 0.f};
    const float rsl2 = 0.25503164113124427f;   // log2(e)/sqrt(32)

    short8v qf[2];
    #pragma unroll
    for (int nf = 0; nf < 2; ++nf)
        qf[nf] = *(const short8v*)(Qb + (size_t)(i0 + nf * 16 + c15) * ldq + head * 32 + g * 8);

    float m_[2] = {-1e30f, -1e30f};
    float l_[2] = {0.f, 0.f};   // per-lane partial; cross-lane reduced at END
    f32x4 acc[2][2];
    acc[0][0] = zf; acc[0][1] = zf; acc[1][0] = zf; acc[1][1] = zf;

    for (int kt = 0; kt < KT; ++kt) {
        const int k0 = (w * KT + kt) * 64;
        short8v kf[4];
        #pragma unroll
        for (int mf = 0; mf < 4; ++mf)
            kf[mf] = *(const short8v*)(Kh + (size_t)(k0 + mf * 16 + c15) * ldk + g * 8);
        f32x4 s[4][2];
        __builtin_amdgcn_s_setprio(1);
        #pragma unroll
        for (int mf = 0; mf < 4; ++mf)
            #pragma unroll
            for (int nf = 0; nf < 2; ++nf)
                s[mf][nf] = __builtin_amdgcn_mfma_f32_16x16x32_bf16(kf[mf], qf[nf], zf, 0, 0, 0);
        __builtin_amdgcn_s_setprio(0);
        #pragma unroll
        for (int nf = 0; nf < 2; ++nf) {
            const unsigned short* bp = biasb + (size_t)(i0 + nf * 16 + c15) * 3072 + k0;
            #pragma unroll
            for (int mf = 0; mf < 4; ++mf) {
                uint2 bv = *(const uint2*)(bp + mf * 16 + g * 4);
                s[mf][nf][0] = s[mf][nf][0] * rsl2 + __uint_as_float(bv.x << 16);
                s[mf][nf][1] = s[mf][nf][1] * rsl2 + __uint_as_float(bv.x & 0xffff0000u);
                s[mf][nf][2] = s[mf][nf][2] * rsl2 + __uint_as_float(bv.y << 16);
                s[mf][nf][3] = s[mf][nf][3] * rsl2 + __uint_as_float(bv.y & 0xffff0000u);
            }
        }
        #pragma unroll
        for (int nf = 0; nf < 2; ++nf) {
            float t0 = fmaxf(fmaxf(s[0][nf][0], s[0][nf][1]), fmaxf(s[0][nf][2], s[0][nf][3]));
            float t1 = fmaxf(fmaxf(s[1][nf][0], s[1][nf][1]), fmaxf(s[1][nf][2], s[1][nf][3]));
            float t2 = fmaxf(fmaxf(s[2][nf][0], s[2][nf][1]), fmaxf(s[2][nf][2], s[2][nf][3]));
            float t3 = fmaxf(fmaxf(s[3][nf][0], s[3][nf][1]), fmaxf(s[3][nf][2], s[3][nf][3]));
            float tmax = fmaxf(fmaxf(t0, t1), fmaxf(t2, t3));
            tmax = fmaxf(tmax, __shfl_xor(tmax, 16));
            tmax = fmaxf(tmax, __shfl_xor(tmax, 32));
            if (!__all(tmax <= m_[nf] + 8.0f)) {       // defer-max (T13)
                float mn = fmaxf(m_[nf], tmax);
                float scl = EXP2(m_[nf] - mn);
                m_[nf] = mn;
                l_[nf] *= scl;
                #pragma unroll
                for (int mf = 0; mf < 2; ++mf) {
                    acc[mf][nf][0] *= scl; acc[mf][nf][1] *= scl;
                    acc[mf][nf][2] *= scl; acc[mf][nf][3] *= scl;
                }
            }
            float mcur = m_[nf];
            float ps0 = 0.f, ps1 = 0.f, ps2 = 0.f, ps3 = 0.f;
            #pragma unroll
            for (int mf = 0; mf < 4; ++mf) {
                float p0 = EXP2(s[mf][nf][0] - mcur);
                float p1 = EXP2(s[mf][nf][1] - mcur);
                float p2 = EXP2(s[mf][nf][2] - mcur);
                float p3 = EXP2(s[mf][nf][3] - mcur);
                s[mf][nf][0] = p0; s[mf][nf][1] = p1;
                s[mf][nf][2] = p2; s[mf][nf][3] = p3;
                ps0 += p0; ps1 += p1; ps2 += p2; ps3 += p3;
            }
            l_[nf] += (ps0 + ps1) + (ps2 + ps3);   // per-lane partial, NO shfl here
            const int q = nf * 16 + c15;
            #pragma unroll
            for (int mf = 0; mf < 4; ++mf) {
                uint2 pv;
                pv.x = pack_b16(s[mf][nf][0], s[mf][nf][1]);
                pv.y = pack_b16(s[mf][nf][2], s[mf][nf][3]);
                *(uint2*)(P_lds + q * 72 + mf * 16 + g * 4) = pv;
            }
        }
        #pragma unroll
        for (int ks = 0; ks < 2; ++ks) {
            short8v pB[2], vA[2];
            #pragma unroll
            for (int nf = 0; nf < 2; ++nf)
                pB[nf] = *(const short8v*)(P_lds + (nf * 16 + c15) * 72 + ks * 32 + g * 8);
            #pragma unroll
            for (int mf = 0; mf < 2; ++mf)
                vA[mf] = *(const short8v*)(VTh + (size_t)(mf * 16 + c15) * 3072 + k0 + ks * 32 + g * 8);
            __builtin_amdgcn_s_setprio(1);
            #pragma unroll
            for (int mf = 0; mf < 2; ++mf)
                #pragma unroll
                for (int nf = 0; nf < 2; ++nf)
                    acc[mf][nf] = __builtin_amdgcn_mfma_f32_16x16x32_bf16(vA[mf], pB[nf], acc[mf][nf], 0, 0, 0);
            __builtin_amdgcn_s_setprio(0);
        }
    }

    // partials -> LDS, cross-split combine
    float* Olds = (float*)P_all;
    #pragma unroll
    for (int nf = 0; nf < 2; ++nf) {
        float lv = l_[nf];
        lv += __shfl_xor(lv, 16);
        lv += __shfl_xor(lv, 32);
        int q = nf * 16 + c15;
        #pragma unroll
        for (int mf = 0; mf < 2; ++mf)
            *(f32x4*)(Olds + w * 1152 + q * 36 + mf * 16 + g * 4) = acc[mf][nf];
        if (g == 0) {
            ml[w * 64 + q] = m_[nf];
            ml[w * 64 + 32 + q] = lv;
        }
    }
    __syncthreads();
    if (tid < 256) {
        int q = tid >> 3, d0 = (tid & 7) * 4;
        float M = -1e30f;
        #pragma unroll
        for (int s = 0; s < SPLIT; ++s) M = fmaxf(M, ml[s * 64 + q]);
        float wsv[SPLIT];
        float L = 0.f;
        #pragma unroll
        for (int s = 0; s < SPLIT; ++s) {
            float wv = EXP2(ml[s * 64 + q] - M);
            wsv[s] = wv;
            L += wv * ml[s * 64 + 32 + q];
        }
        float invL = 1.0f / L;
        float v0 = 0, v1 = 0, v2 = 0, v3 = 0;
        #pragma unroll
        for (int s = 0; s < SPLIT; ++s) {
            const float* op = Olds + s * 1152 + q * 36 + d0;
            v0 += wsv[s] * op[0]; v1 += wsv[s] * op[1];
            v2 += wsv[s] * op[2]; v3 += wsv[s] * op[3];
        }
        uint2 pk;
        pk.x = pack_b16(v0 * invL, v1 * invL);
        pk.y = pack_b16(v2 * invL, v3 * invL);
        *(uint2*)(out + (size_t)(i0 + q) * 256 + head * 32 + d0) = pk;
    }
}

extern "C" void kernel_launch(void* const* d_in, const int* in_sizes, int n_in,
                              void* d_out, int out_size, void* d_ws, size_t ws_size,
                              hipStream_t stream)
{
    const float* x        = (const float*)d_in[0];
    const float* C        = (const float*)d_in[1];
    const int*   sidx     = (const int*)d_in[2];
    const unsigned char* mask = (const unsigned char*)d_in[3];
    const float* proj_W   = (const float*)d_in[4];
    const float* proj_b   = (const float*)d_in[5];
    const float* peW      = (const float*)d_in[6];
    const float* peb      = (const float*)d_in[7];
    const float* peg      = (const float*)d_in[8];
    const float* pebt     = (const float*)d_in[9];
    const float* pe_gate  = (const float*)d_in[10];
    const float* alpha_nn = (const float*)d_in[11];
    const float* beta_sn  = (const float*)d_in[12];
    const float* sqW      = (const float*)d_in[13];
    const float* sqb      = (const float*)d_in[14];
    const float* sn_Win   = (const float*)d_in[15];
    const float* sn_bin   = (const float*)d_in[16];
    const float* sn_Wout  = (const float*)d_in[17];
    const float* sn_bout  = (const float*)d_in[18];
    const float* nn_Win   = (const float*)d_in[19];
    const float* nn_bin   = (const float*)d_in[20];
    const float* nn_Wout  = (const float*)d_in[21];
    const float* nn_bout  = (const float*)d_in[22];
    const float* ln_s_g   = (const float*)d_in[23];
    const float* ln_s_b   = (const float*)d_in[24];
    const float* ln_n1_g  = (const float*)d_in[25];
    const float* ln_n1_b  = (const float*)d_in[26];
    const float* ln_n2_g  = (const float*)d_in[27];
    const float* ln_n2_b  = (const float*)d_in[28];
    const float* ffn_W1   = (const float*)d_in[29];
    const float* ffn_b1   = (const float*)d_in[30];
    const float* ffn_W2   = (const float*)d_in[31];
    const float* ffn_b2   = (const float*)d_in[32];
    const float* ffs_W1   = (const float*)d_in[33];
    const float* ffs_b1   = (const float*)d_in[34];
    const float* ffs_W2   = (const float*)d_in[35];
    const float* ffs_b2   = (const float*)d_in[36];
    const float* ln_og    = (const float*)d_in[37];
    const float* ln_ob    = (const float*)d_in[38];

    float* ws = (float*)d_ws;
    float* h       = ws;                                          // 786432 f
    float* sinkq   = ws + 786432;                                 // 65536
    float* maskadd = ws + 851968;                                 // 4096
    unsigned short* Cnb    = (unsigned short*)(ws + 856064);      // 393216 f
    unsigned short* hb     = (unsigned short*)(ws + 1249280);     // 393216 f
    unsigned short* hnb    = (unsigned short*)(ws + 1642496);     // 393216 f
    unsigned short* attnob = (unsigned short*)(ws + 2035712);     // 393216 f
    unsigned short* sqnb   = (unsigned short*)(ws + 2428928);     // 32768 f
    unsigned short* sgb    = (unsigned short*)(ws + 2461696);     // 32768 f
    unsigned short* sinkqb = (unsigned short*)(ws + 2494464);     // 32768 f
    unsigned short* VTb    = (unsigned short*)(ws + 2527232);     // 393216 f
    unsigned short* CTb    = (unsigned short*)(ws + 2920448);     // 393216 f
    unsigned short* biasb  = (unsigned short*)(ws + 3313664);     // 4718592 f (3072x3072 bf16)
    unsigned short* wb     = (unsigned short*)(ws + 8032256);     // 2392064 f
    float* big     = ws + 10424320;                               // 1572864 f union
    unsigned short* sqWb    = wb;
    unsigned short* snWinb  = wb + 65536;
    unsigned short* snWoutb = wb + 655360;
    unsigned short* nnWinb  = wb + 851968;
    unsigned short* nnWoutb = wb + 1441792;
    unsigned short* ffnW1b  = wb + 1638400;
    unsigned short* ffnW2b  = wb + 2424832;
    unsigned short* ffsW1b  = wb + 3211264;
    unsigned short* ffsW2b  = wb + 3997696;
    unsigned short* q_sb  = (unsigned short*)big;                 // 256x256
    unsigned short* kv_sb = (unsigned short*)(big + 32768);       // 3072x512
    unsigned short* mid_sb= (unsigned short*)(big + 819200);      // 256x1024
    unsigned short* qkvb  = (unsigned short*)big;                 // 3072x768
    unsigned short* midb  = (unsigned short*)big;                 // 3072x1024

    dim3 b256(256), b512(512);

    CvtJobs cj;
    cj.src[0] = sqW;     cj.dst[0] = sqWb;    cj.cnt4[0] = 16384;
    cj.src[1] = sn_Win;  cj.dst[1] = snWinb;  cj.cnt4[1] = 147456;
    cj.src[2] = sn_Wout; cj.dst[2] = snWoutb; cj.cnt4[2] = 49152;
    cj.src[3] = nn_Win;  cj.dst[3] = nnWinb;  cj.cnt4[3] = 147456;
    cj.src[4] = nn_Wout; cj.dst[4] = nnWoutb; cj.cnt4[4] = 49152;
    cj.src[5] = ffn_W1;  cj.dst[5] = ffnW1b;  cj.cnt4[5] = 196608;
    cj.src[6] = ffn_W2;  cj.dst[6] = ffnW2b;  cj.cnt4[6] = 196608;
    cj.src[7] = ffs_W1;  cj.dst[7] = ffsW1b;  cj.cnt4[7] = 196608;
    cj.src[8] = ffs_W2;  cj.dst[8] = ffsW2b;  cj.cnt4[8] = 196608;
    cvt_all_kernel<<<4672, b256, 0, stream>>>(cj, 1196032);

    maskadd_kernel<<<12, b256, 0, stream>>>(mask, maskadd);
    node_encode_kernel<<<N_NODES, b256, 0, stream>>>(x, C, mask, proj_W, proj_b, peW, peb, peg, pebt, pe_gate, h, hb);
    gather_b16_kernel<<<S_SINK, b256, 0, stream>>>(h, sidx, sgb);
    gemm_mfma_kernel<<<dim3(4, 4), b256, 0, stream>>>(sgb, 256, sqWb, 256, sqb, nullptr, nullptr, 1.0f, sinkq, nullptr, 256, 0, 256, 0);
    cn_kernel<<<N_NODES, b256, 0, stream>>>(C, Cnb);
    transpose_b16_kernel<<<dim3(96, 8), b256, 0, stream>>>(C, beta_sn, maskadd, CTb);
    gemm_mfma_kernel<<<dim3(48, 48), b256, 0, stream>>>(Cnb, 256, Cnb, 256, maskadd, nullptr, alpha_nn, LOG2E, biasb, nullptr, 3072, 1, 256, 0);

    for (int l = 0; l < 3; ++l) {
        // ---- sink branch ----
        ln_b16_kernel<<<S_SINK, b256, 0, stream>>>(sinkq, ln_s_g + l * 256, ln_s_b + l * 256, sqnb);
        gemm_mfma_kernel<<<dim3(4, 4), b256, 0, stream>>>(sqnb, 256, snWinb + (size_t)l * 196608, 256, sn_bin + l * 768, nullptr, nullptr, 1.0f, q_sb, nullptr, 256, 1, 256, 0);
        gemm_mfma_kernel<<<dim3(8, 48), b256, 0, stream>>>(hb, 256, snWinb + (size_t)l * 196608 + 65536, 256, sn_bin + l * 768 + 256, nullptr, nullptr, 1.0f, kv_sb, nullptr, 512, 1, 256, 0);
        prep_vt_kernel<<<dim3(48, 8), b256, 0, stream>>>(kv_sb, 512, 256, VTb);
        attn_mfma_kernel<8><<<dim3(8, 8), b512, 0, stream>>>(q_sb, 256, kv_sb, 512, VTb, CTb, attnob);
        gemm_mfma_kernel<<<dim3(4, 4), b256, 0, stream>>>(attnob, 256, snWoutb + (size_t)l * 65536, 256, sn_bout + l * 256, sinkq, nullptr, 1.0f, sinkq, sinkqb, 256, 0, 256, 0);
        gemm_mfma_kernel<<<dim3(16, 4), b256, 0, stream>>>(sinkqb, 256, ffsW1b + (size_t)l * 262144, 256, ffs_b1 + l * 1024, nullptr, nullptr, 1.0f, mid_sb, nullptr, 1024, 1, 256, 1);
        gemm_mfma_kernel<<<dim3(4, 4), b256, 0, stream>>>(mid_sb, 1024, ffsW2b + (size_t)l * 262144, 1024, ffs_b2 + l * 256, sinkq, nullptr, 1.0f, sinkq, nullptr, 256, 0, 1024, 0);

        // ---- node branch ----
        ln_b16_kernel<<<N_NODES, b256, 0, stream>>>(h, ln_n1_g + l * 256, ln_n1_b + l * 256, hnb);
        gemm_mfma_kernel<<<dim3(12, 48), b256, 0, stream>>>(hnb, 256, nnWinb + (size_t)l * 196608, 256, nn_bin + l * 768, nullptr, nullptr, 1.0f, qkvb, nullptr, 768, 1, 256, 0);
        prep_vt_kernel<<<dim3(48, 8), b256, 0, stream>>>(qkvb, 768, 512, VTb);
        attn_mfma_kernel<8><<<dim3(96, 8), b512, 0, stream>>>(qkvb, 768, qkvb + 256, 768, VTb, biasb, attnob);
        gemm_mfma_kernel<<<dim3(4, 48), b256, 0, stream>>>(attnob, 256, nnWoutb + (size_t)l * 65536, 256, nn_bout + l * 256, h, nullptr, 1.0f, h, nullptr, 256, 0, 256, 0);
        ln_b16_kernel<<<N_NODES, b256, 0, stream>>>(h, ln_n2_g + l * 256, ln_n2_b + l * 256, hnb);
        gemm_mfma_kernel<<<dim3(16, 48), b256, 0, stream>>>(hnb, 256, ffnW1b + (size_t)l * 262144, 256, ffn_b1 + l * 1024, nullptr, nullptr, 1.0f, midb, nullptr, 1024, 1, 256, 1);
        gemm_mfma_kernel<<<dim3(4, 48), b256, 0, stream>>>(midb, 1024, ffnW2b + (size_t)l * 262144, 1024, ffn_b2 + l * 256, h, nullptr, 1.0f, h, hb, 256, 0, 1024, 0);
    }

    ln_out_kernel<<<S_SINK, b256, 0, stream>>>(sinkq, ln_og, ln_ob, (float*)d_out);
}